// Round 12
// baseline (654.620 us; speedup 1.0000x reference)
//
#include <hip/hip_runtime.h>

typedef unsigned short u16;
typedef unsigned int u32;
typedef __attribute__((ext_vector_type(8))) __bf16 bf16x8;
typedef __attribute__((ext_vector_type(4))) float f32x4;
typedef __attribute__((ext_vector_type(2))) u32 u32x2;
typedef __attribute__((ext_vector_type(4))) u32 u32x4;

__device__ __forceinline__ u16 f2bf(float f) {
    u32 u = __float_as_uint(f);
    u = (u + 0x7FFFu + ((u >> 16) & 1u)) >> 16;
    return (u16)u;
}
__device__ __forceinline__ bf16x8 cvt2bf(f32x4 lo, f32x4 hi) {
    bf16x8 r;
    r[0] = (__bf16)lo[0]; r[1] = (__bf16)lo[1]; r[2] = (__bf16)lo[2]; r[3] = (__bf16)lo[3];
    r[4] = (__bf16)hi[0]; r[5] = (__bf16)hi[1]; r[6] = (__bf16)hi[2]; r[7] = (__bf16)hi[3];
    return r;
}
__device__ __forceinline__ bf16x8 load8f_bf(const float* p) {
    return cvt2bf(*(const f32x4*)p, *(const f32x4*)(p + 4));
}
__device__ __forceinline__ u32 pk2(float x, float y) {
    __bf16 bx = (__bf16)x, by = (__bf16)y;
    return (u32)__builtin_bit_cast(u16, bx) | ((u32)__builtin_bit_cast(u16, by) << 16);
}

// packed A-fragment (W^T) layout, per layer: idx = ((s*4 + m)*64 + lane)*8 + j
// value = W[k][16*m + (lane&15)], k = s*32 + (lane>>4)*8 + j
#define PK_EW1 0
#define PK_EW2 12288
#define PK_EW3 16384
#define PK_NW1 20480
#define PK_NW2 28672
#define PK_NW3 32768
#define PK_TOTAL 36864

__global__ void pack_weights_kernel(const float* __restrict__ eW1, const float* __restrict__ eW2,
                                    const float* __restrict__ eW3, const float* __restrict__ nW1,
                                    const float* __restrict__ nW2, const float* __restrict__ nW3,
                                    u16* __restrict__ P) {
    int idx = blockIdx.x * blockDim.x + threadIdx.x;
    if (idx >= PK_TOTAL) return;
    const float* W; int base;
    if (idx < PK_EW2)      { W = eW1; base = PK_EW1; }
    else if (idx < PK_EW3) { W = eW2; base = PK_EW2; }
    else if (idx < PK_NW1) { W = eW3; base = PK_EW3; }
    else if (idx < PK_NW2) { W = nW1; base = PK_NW1; }
    else if (idx < PK_NW3) { W = nW2; base = PK_NW2; }
    else                   { W = nW3; base = PK_NW3; }
    int r = idx - base;
    int j = r & 7, lane = (r >> 3) & 63, m = (r >> 9) & 3, s = r >> 11;
    int k = s * 32 + (lane >> 4) * 8 + j;
    int col = 16 * m + (lane & 15);
    P[idx] = f2bf(W[k * 64 + col]);
}

// ---------------- CSR build ----------------
__global__ void degree_kernel(const int* __restrict__ edge_idx, int* __restrict__ deg, int E) {
    int e = blockIdx.x * blockDim.x + threadIdx.x;
    if (e < E) atomicAdd(&deg[edge_idx[2 * e]], 1);
}

__global__ void scan_blocks_kernel(const int* __restrict__ deg, int* __restrict__ off,
                                   int* __restrict__ partials, int N) {
    __shared__ int sh[256];
    const int t = threadIdx.x;
    const int g = blockIdx.x * 256 + t;
    int v = (g < N) ? deg[g] : 0;
    sh[t] = v;
    __syncthreads();
#pragma unroll
    for (int d = 1; d < 256; d <<= 1) {
        int add = (t >= d) ? sh[t - d] : 0;
        __syncthreads();
        sh[t] += add;
        __syncthreads();
    }
    if (g < N) off[g] = sh[t] - v;
    if (t == 255) partials[blockIdx.x] = sh[255];
}

__global__ void scan_partials_kernel(int* __restrict__ partials, int nparts) {
    __shared__ int sh[256];
    const int t = threadIdx.x;
    int v = (t < nparts) ? partials[t] : 0;
    sh[t] = v;
    __syncthreads();
#pragma unroll
    for (int d = 1; d < 256; d <<= 1) {
        int add = (t >= d) ? sh[t - d] : 0;
        __syncthreads();
        sh[t] += add;
        __syncthreads();
    }
    if (t < nparts) partials[t] = sh[t] - v;
}

__global__ void finalize_offsets_kernel(int* __restrict__ off, int* __restrict__ pos,
                                        const int* __restrict__ partials, int N, int E) {
    int g = blockIdx.x * blockDim.x + threadIdx.x;
    if (g < N) {
        int o = off[g] + partials[g >> 8];
        off[g] = o;
        pos[g] = o;
    }
    if (g == 0) off[N] = E;
}

__global__ void fill_csr_kernel(const int* __restrict__ edge_idx, int* __restrict__ pos,
                                int* __restrict__ csr, int E) {
    int e = blockIdx.x * blockDim.x + threadIdx.x;
    if (e < E) {
        int slot = atomicAdd(&pos[edge_idx[2 * e]], 1);
        csr[slot] = e;
    }
}

// ---------------- gather (fp32 out_edge, csr-indexed) — R7's proven kernel ----------------
__global__ __launch_bounds__(256) void gather_csr_kernel(
    const float* __restrict__ proc_edge, const int* __restrict__ off,
    const int* __restrict__ csr, u16* __restrict__ nodal16, int N)
{
    const int wid = threadIdx.x >> 6, lane = threadIdx.x & 63;
    const int n = blockIdx.x * 4 + wid;
    if (n >= N) return;
    const int r = lane >> 4;
    const int q = lane & 15;
    const int beg = off[n], end = off[n + 1];
    f32x4 v0 = 0.0f, v1 = 0.0f, v2 = 0.0f, v3 = 0.0f;
    int j = beg + r;
    for (; j + 12 < end; j += 16) {
        int e0 = csr[j], e1 = csr[j + 4], e2 = csr[j + 8], e3 = csr[j + 12];
        v0 += *(const f32x4*)(proc_edge + (size_t)e0 * 64 + q * 4);
        v1 += *(const f32x4*)(proc_edge + (size_t)e1 * 64 + q * 4);
        v2 += *(const f32x4*)(proc_edge + (size_t)e2 * 64 + q * 4);
        v3 += *(const f32x4*)(proc_edge + (size_t)e3 * 64 + q * 4);
    }
    for (; j < end; j += 4) {
        int e0 = csr[j];
        v0 += *(const f32x4*)(proc_edge + (size_t)e0 * 64 + q * 4);
    }
    v0 += v1; v2 += v3; v0 += v2;
#pragma unroll
    for (int i = 0; i < 4; ++i) {
        v0[i] += __shfl_xor(v0[i], 16, 64);
        v0[i] += __shfl_xor(v0[i], 32, 64);
    }
    if (r == 0) {
        u32x2 pv; pv[0] = pk2(v0[0], v0[1]); pv[1] = pk2(v0[2], v0[3]);
        *(u32x2*)(nodal16 + (size_t)n * 64 + q * 4) = pv;
    }
}

// ---------------- edge MLP + LN: async global_load_lds staging (16 edges/wave) ----------------
__global__ __launch_bounds__(256) void edge_mlp_kernel(
    const float* __restrict__ node_feat, const float* __restrict__ edge_feat,
    const int* __restrict__ edge_idx, const u16* __restrict__ Pw,
    const float* __restrict__ b1g, const float* __restrict__ b2g, const float* __restrict__ b3g,
    const float* __restrict__ gg, const float* __restrict__ betag,
    float* __restrict__ out_edge, int E)
{
    __shared__ u16 wlds[12288];     // 24 KB: phase A = EW1; phase B = EW2|EW3
    __shared__ u16 stage[4][6144];  // 12 KB per wave: 12 slots x 1 KB (lane*16B each)
    __shared__ float params[5][64];
    const int tid = threadIdx.x;
    // ---- stage layer-1 weights (24 KB)
#pragma unroll
    for (int i = 0; i < 6; ++i) {
        int idx = i * 256 + tid;
        *(u32x4*)(wlds + (size_t)idx * 8) = *(const u32x4*)(Pw + PK_EW1 + (size_t)idx * 8);
    }
    if (tid < 64) {
        params[0][tid] = b1g[tid];
        params[1][tid] = b2g[tid];
        params[2][tid] = b3g[tid];
        params[3][tid] = gg[tid];
        params[4][tid] = betag[tid];
    }
    __syncthreads();

    const int wid = tid >> 6, lane = tid & 63;
    const int er = lane & 15, a = lane >> 4;
    const int e0 = blockIdx.x * 64 + wid * 16 + er;
    const int e = (e0 < E) ? e0 : (E - 1);
    int2 ii = *(const int2*)(edge_idx + 2 * e);
    const int cn = ii.x, sn = ii.y;
    u16* st = stage[wid];
    const int swz = (er & 7) << 4;

    // ---- async-stage the wave's 12 x 1KB layer-1 operand chunks (VGPR-free, all in flight)
    // slot 2s+h holds lane's floats [s*32 + a*8 + h*4 .. +4) of the K=192 concat row
#pragma unroll
    for (int s = 0; s < 6; ++s) {
        const float* base;
        if (s < 2)      base = edge_feat + (size_t)e * 64 + s * 32 + a * 8;
        else if (s < 4) base = node_feat + (size_t)cn * 64 + (s - 2) * 32 + a * 8;
        else            base = node_feat + (size_t)sn * 64 + (s - 4) * 32 + a * 8;
        __builtin_amdgcn_global_load_lds(
            (const __attribute__((address_space(1))) void*)base,
            (__attribute__((address_space(3))) void*)(st + (2 * s) * 512), 16, 0, 0);
        __builtin_amdgcn_global_load_lds(
            (const __attribute__((address_space(1))) void*)(base + 4),
            (__attribute__((address_space(3))) void*)(st + (2 * s + 1) * 512), 16, 0, 0);
    }
    __builtin_amdgcn_sched_barrier(0);
    asm volatile("s_waitcnt vmcnt(0)" ::: "memory");
    __builtin_amdgcn_sched_barrier(0);

    // ---- layer 1: K = 192, read staged chunks back at lane*16
    f32x4 acc[4];
#pragma unroll
    for (int m = 0; m < 4; ++m) acc[m] = 0.0f;
#pragma unroll
    for (int s = 0; s < 6; ++s) {
        f32x4 lo = *(const f32x4*)((const char*)st + (2 * s) * 1024 + lane * 16);
        f32x4 hi = *(const f32x4*)((const char*)st + (2 * s + 1) * 1024 + lane * 16);
        bf16x8 bf = cvt2bf(lo, hi);
#pragma unroll
        for (int m = 0; m < 4; ++m) {
            bf16x8 af = *(const bf16x8*)(wlds + ((s * 4 + m) * 64 + lane) * 8);
            acc[m] = __builtin_amdgcn_mfma_f32_16x16x32_bf16(af, bf, acc[m], 0, 0, 0);
        }
    }
    __syncthreads();   // everyone done with layer-1 weights and stage reads
    // ---- re-stage: EW2 | EW3 (16 KB) into the same buffer
#pragma unroll
    for (int i = 0; i < 4; ++i) {
        int idx = i * 256 + tid;
        *(u32x4*)(wlds + (size_t)idx * 8) = *(const u32x4*)(Pw + PK_EW2 + (size_t)idx * 8);
    }
    __syncthreads();

    // ---- layers 2 & 3 (htile = first 2KB of this wave's stage slot, XOR-swizzled)
    u16* ht = st;
    // bias + relu (layer1) -> tile
#pragma unroll
    for (int m = 0; m < 4; ++m) {
        float v0 = fmaxf(acc[m][0] + params[0][16 * m + 4 * a + 0], 0.0f);
        float v1 = fmaxf(acc[m][1] + params[0][16 * m + 4 * a + 1], 0.0f);
        float v2 = fmaxf(acc[m][2] + params[0][16 * m + 4 * a + 2], 0.0f);
        float v3 = fmaxf(acc[m][3] + params[0][16 * m + 4 * a + 3], 0.0f);
        u32x2 pv; pv[0] = pk2(v0, v1); pv[1] = pk2(v2, v3);
        int boff = (er * 128 + (16 * m + 4 * a) * 2) ^ swz;
        *(u32x2*)((char*)ht + boff) = pv;
    }
    // layer 2: K = 64
    f32x4 a2[4];
#pragma unroll
    for (int m = 0; m < 4; ++m) a2[m] = 0.0f;
#pragma unroll
    for (int s = 0; s < 2; ++s) {
        int boff = (er * 128 + s * 64 + a * 16) ^ swz;
        bf16x8 bf = *(const bf16x8*)((char*)ht + boff);
#pragma unroll
        for (int m = 0; m < 4; ++m) {
            bf16x8 af = *(const bf16x8*)(wlds + ((s * 4 + m) * 64 + lane) * 8);
            a2[m] = __builtin_amdgcn_mfma_f32_16x16x32_bf16(af, bf, a2[m], 0, 0, 0);
        }
    }
    // bias + relu (layer2) -> tile (same-wave DS ops are in-order)
#pragma unroll
    for (int m = 0; m < 4; ++m) {
        float v0 = fmaxf(a2[m][0] + params[1][16 * m + 4 * a + 0], 0.0f);
        float v1 = fmaxf(a2[m][1] + params[1][16 * m + 4 * a + 1], 0.0f);
        float v2 = fmaxf(a2[m][2] + params[1][16 * m + 4 * a + 2], 0.0f);
        float v3 = fmaxf(a2[m][3] + params[1][16 * m + 4 * a + 3], 0.0f);
        u32x2 pv; pv[0] = pk2(v0, v1); pv[1] = pk2(v2, v3);
        int boff = (er * 128 + (16 * m + 4 * a) * 2) ^ swz;
        *(u32x2*)((char*)ht + boff) = pv;
    }
    // layer 3: K = 64 (no relu)
    f32x4 a3[4];
#pragma unroll
    for (int m = 0; m < 4; ++m) a3[m] = 0.0f;
#pragma unroll
    for (int s = 0; s < 2; ++s) {
        int boff = (er * 128 + s * 64 + a * 16) ^ swz;
        bf16x8 bf = *(const bf16x8*)((char*)ht + boff);
#pragma unroll
        for (int m = 0; m < 4; ++m) {
            bf16x8 af = *(const bf16x8*)(wlds + 4096 + ((s * 4 + m) * 64 + lane) * 8);
            a3[m] = __builtin_amdgcn_mfma_f32_16x16x32_bf16(af, bf, a3[m], 0, 0, 0);
        }
    }
    // LayerNorm + store
    float vals[16], sum = 0.0f, ssq = 0.0f;
#pragma unroll
    for (int m = 0; m < 4; ++m)
#pragma unroll
        for (int r = 0; r < 4; ++r) {
            float v = a3[m][r] + params[2][16 * m + 4 * a + r];
            vals[4 * m + r] = v; sum += v; ssq += v * v;
        }
    sum += __shfl_xor(sum, 16, 64); sum += __shfl_xor(sum, 32, 64);
    ssq += __shfl_xor(ssq, 16, 64); ssq += __shfl_xor(ssq, 32, 64);
    const float mean = sum * 0.015625f;
    const float var = ssq * 0.015625f - mean * mean;
    const float inv = rsqrtf(var + 1e-5f);
    if (e0 < E) {
#pragma unroll
        for (int m = 0; m < 4; ++m) {
            f32x4 o;
#pragma unroll
            for (int r = 0; r < 4; ++r) {
                int f = 16 * m + 4 * a + r;
                o[r] = (vals[4 * m + r] - mean) * inv * params[3][f] + params[4][f];
            }
            *(f32x4*)(out_edge + (size_t)e0 * 64 + 16 * m + 4 * a) = o;
        }
    }
}

// ---------------- node MLP + LN (nodal16 bf16; linear reads) — R7 verbatim ----------------
__global__ __launch_bounds__(256) void node_mlp_kernel(
    const float* __restrict__ node_feat, const u16* __restrict__ nodal16,
    const u16* __restrict__ Pw,
    const float* __restrict__ b1g, const float* __restrict__ b2g, const float* __restrict__ b3g,
    const float* __restrict__ gg, const float* __restrict__ betag,
    float* __restrict__ out_node, int N)
{
    __shared__ float params[5][64];
    __shared__ u16 htile[4][1024];
    const int tid = threadIdx.x;
    if (tid < 64) {
        params[0][tid] = b1g[tid];
        params[1][tid] = b2g[tid];
        params[2][tid] = b3g[tid];
        params[3][tid] = gg[tid];
        params[4][tid] = betag[tid];
    }
    __syncthreads();
    const int wid = tid >> 6, lane = tid & 63;
    const int er = lane & 15, a = lane >> 4;
    const int nbase = (blockIdx.x * 4 + wid) * 16;
    if (nbase >= N) return;
    const int n = nbase + er;
    u16* ht = htile[wid];
    const int swz = (er & 7) << 4;

    f32x4 acc[4];
#pragma unroll
    for (int m = 0; m < 4; ++m) acc[m] = 0.0f;

#pragma unroll
    for (int s = 0; s < 4; ++s) {
        bf16x8 af[4];
#pragma unroll
        for (int m = 0; m < 4; ++m)
            af[m] = *(const bf16x8*)(Pw + PK_NW1 + ((s * 4 + m) * 64 + lane) * 8);
        bf16x8 bf;
        if (s < 2) bf = load8f_bf(node_feat + (size_t)n * 64 + s * 32 + a * 8);
        else       bf = *(const bf16x8*)(nodal16 + (size_t)n * 64 + (s - 2) * 32 + a * 8);
#pragma unroll
        for (int m = 0; m < 4; ++m)
            acc[m] = __builtin_amdgcn_mfma_f32_16x16x32_bf16(af[m], bf, acc[m], 0, 0, 0);
    }
#pragma unroll
    for (int m = 0; m < 4; ++m) {
        float v0 = fmaxf(acc[m][0] + params[0][16 * m + 4 * a + 0], 0.0f);
        float v1 = fmaxf(acc[m][1] + params[0][16 * m + 4 * a + 1], 0.0f);
        float v2 = fmaxf(acc[m][2] + params[0][16 * m + 4 * a + 2], 0.0f);
        float v3 = fmaxf(acc[m][3] + params[0][16 * m + 4 * a + 3], 0.0f);
        u32x2 pv; pv[0] = pk2(v0, v1); pv[1] = pk2(v2, v3);
        int boff = (er * 128 + (16 * m + 4 * a) * 2) ^ swz;
        *(u32x2*)((char*)ht + boff) = pv;
    }

#pragma unroll
    for (int m = 0; m < 4; ++m) acc[m] = 0.0f;
#pragma unroll
    for (int s = 0; s < 2; ++s) {
        bf16x8 af[4];
#pragma unroll
        for (int m = 0; m < 4; ++m)
            af[m] = *(const bf16x8*)(Pw + PK_NW2 + ((s * 4 + m) * 64 + lane) * 8);
        int boff = (er * 128 + s * 64 + a * 16) ^ swz;
        bf16x8 bf = *(const bf16x8*)((char*)ht + boff);
#pragma unroll
        for (int m = 0; m < 4; ++m)
            acc[m] = __builtin_amdgcn_mfma_f32_16x16x32_bf16(af[m], bf, acc[m], 0, 0, 0);
    }
#pragma unroll
    for (int m = 0; m < 4; ++m) {
        float v0 = fmaxf(acc[m][0] + params[1][16 * m + 4 * a + 0], 0.0f);
        float v1 = fmaxf(acc[m][1] + params[1][16 * m + 4 * a + 1], 0.0f);
        float v2 = fmaxf(acc[m][2] + params[1][16 * m + 4 * a + 2], 0.0f);
        float v3 = fmaxf(acc[m][3] + params[1][16 * m + 4 * a + 3], 0.0f);
        u32x2 pv; pv[0] = pk2(v0, v1); pv[1] = pk2(v2, v3);
        int boff = (er * 128 + (16 * m + 4 * a) * 2) ^ swz;
        *(u32x2*)((char*)ht + boff) = pv;
    }

#pragma unroll
    for (int m = 0; m < 4; ++m) acc[m] = 0.0f;
#pragma unroll
    for (int s = 0; s < 2; ++s) {
        bf16x8 af[4];
#pragma unroll
        for (int m = 0; m < 4; ++m)
            af[m] = *(const bf16x8*)(Pw + PK_NW3 + ((s * 4 + m) * 64 + lane) * 8);
        int boff = (er * 128 + s * 64 + a * 16) ^ swz;
        bf16x8 bf = *(const bf16x8*)((char*)ht + boff);
#pragma unroll
        for (int m = 0; m < 4; ++m)
            acc[m] = __builtin_amdgcn_mfma_f32_16x16x32_bf16(af[m], bf, acc[m], 0, 0, 0);
    }
    float vals[16], sum = 0.0f, ssq = 0.0f;
#pragma unroll
    for (int m = 0; m < 4; ++m)
#pragma unroll
        for (int r = 0; r < 4; ++r) {
            float v = acc[m][r] + params[2][16 * m + 4 * a + r];
            vals[4 * m + r] = v; sum += v; ssq += v * v;
        }
    sum += __shfl_xor(sum, 16, 64); sum += __shfl_xor(sum, 32, 64);
    ssq += __shfl_xor(ssq, 16, 64); ssq += __shfl_xor(ssq, 32, 64);
    const float mean = sum * 0.015625f;
    const float var = ssq * 0.015625f - mean * mean;
    const float inv = rsqrtf(var + 1e-5f);
#pragma unroll
    for (int m = 0; m < 4; ++m) {
        f32x4 o;
#pragma unroll
        for (int r = 0; r < 4; ++r) {
            int f = 16 * m + 4 * a + r;
            o[r] = (vals[4 * m + r] - mean) * inv * params[3][f] + params[4][f];
        }
        *(f32x4*)(out_node + (size_t)n * 64 + 16 * m + 4 * a) = o;
    }
}

extern "C" void kernel_launch(void* const* d_in, const int* in_sizes, int n_in,
                              void* d_out, int out_size, void* d_ws, size_t ws_size,
                              hipStream_t stream) {
    const float* node_feat = (const float*)d_in[0];
    const float* edge_feat = (const float*)d_in[1];
    const int* edge_idx  = (const int*)d_in[2];
    const float* eW1 = (const float*)d_in[4];
    const float* eb1 = (const float*)d_in[5];
    const float* eW2 = (const float*)d_in[6];
    const float* eb2 = (const float*)d_in[7];
    const float* eW3 = (const float*)d_in[8];
    const float* eb3 = (const float*)d_in[9];
    const float* eg  = (const float*)d_in[10];
    const float* ebt = (const float*)d_in[11];
    const float* nW1 = (const float*)d_in[12];
    const float* nb1 = (const float*)d_in[13];
    const float* nW2 = (const float*)d_in[14];
    const float* nb2 = (const float*)d_in[15];
    const float* nW3 = (const float*)d_in[16];
    const float* nb3 = (const float*)d_in[17];
    const float* ng  = (const float*)d_in[18];
    const float* nbt = (const float*)d_in[19];

    const int N = in_sizes[0] / 64;
    const int E = in_sizes[1] / 64;
    const int nparts = (N + 255) / 256;

    // ws layout
    char* w = (char*)d_ws;
    int* off      = (int*)w;                    w += (size_t)(N + 1) * 4;
    int* pos      = (int*)w;                    w += (size_t)N * 4;
    int* partials = (int*)w;                    w += 256 * 4;
    int* csr      = (int*)w;                    w += (size_t)E * 4;
    u16* Pw       = (u16*)w;                    w += (size_t)PK_TOTAL * 2;
    w = (char*)(((size_t)w + 255) & ~(size_t)255);
    u16* nodal16  = (u16*)w;                    // N*64 bf16

    float* out_edge = (float*)d_out;
    float* out_node = out_edge + (size_t)E * 64;

    pack_weights_kernel<<<(PK_TOTAL + 255) / 256, 256, 0, stream>>>(eW1, eW2, eW3, nW1, nW2, nW3, Pw);

    // edge MLP (async global_load_lds staging; 64 edges per 256-thread block)
    const int eblocks = (E + 63) / 64;
    edge_mlp_kernel<<<eblocks, 256, 0, stream>>>(node_feat, edge_feat, edge_idx, Pw,
                                                 eb1, eb2, eb3, eg, ebt, out_edge, E);

    // CSR build (pos doubles as degree histogram)
    hipMemsetAsync(pos, 0, (size_t)N * 4, stream);
    degree_kernel<<<(E + 255) / 256, 256, 0, stream>>>(edge_idx, pos, E);
    scan_blocks_kernel<<<nparts, 256, 0, stream>>>(pos, off, partials, N);
    scan_partials_kernel<<<1, 256, 0, stream>>>(partials, nparts);
    finalize_offsets_kernel<<<(N + 255) / 256, 256, 0, stream>>>(off, pos, partials, N, E);
    fill_csr_kernel<<<(E + 255) / 256, 256, 0, stream>>>(edge_idx, pos, csr, E);

    // segment-sum gather (fp32 rows -> bf16 nodal)
    gather_csr_kernel<<<(N + 3) / 4, 256, 0, stream>>>(out_edge, off, csr, nodal16, N);

    const int nblocks = (N + 63) / 64;
    node_mlp_kernel<<<nblocks, 256, 0, stream>>>(node_feat, nodal16, Pw,
                                                 nb1, nb2, nb3, ng, nbt, out_node, N);
}

// Round 13
// 637.537 us; speedup vs baseline: 1.0268x; 1.0268x over previous
//
#include <hip/hip_runtime.h>

typedef unsigned short u16;
typedef unsigned int u32;
typedef __attribute__((ext_vector_type(8))) __bf16 bf16x8;
typedef __attribute__((ext_vector_type(4))) float f32x4;
typedef __attribute__((ext_vector_type(2))) u32 u32x2;
typedef __attribute__((ext_vector_type(4))) u32 u32x4;

__device__ __forceinline__ u16 f2bf(float f) {
    u32 u = __float_as_uint(f);
    u = (u + 0x7FFFu + ((u >> 16) & 1u)) >> 16;
    return (u16)u;
}
__device__ __forceinline__ bf16x8 cvt2bf(f32x4 lo, f32x4 hi) {
    bf16x8 r;
    r[0] = (__bf16)lo[0]; r[1] = (__bf16)lo[1]; r[2] = (__bf16)lo[2]; r[3] = (__bf16)lo[3];
    r[4] = (__bf16)hi[0]; r[5] = (__bf16)hi[1]; r[6] = (__bf16)hi[2]; r[7] = (__bf16)hi[3];
    return r;
}
__device__ __forceinline__ bf16x8 load8f_bf(const float* p) {
    return cvt2bf(*(const f32x4*)p, *(const f32x4*)(p + 4));
}
__device__ __forceinline__ u32 pk2(float x, float y) {
    __bf16 bx = (__bf16)x, by = (__bf16)y;
    return (u32)__builtin_bit_cast(u16, bx) | ((u32)__builtin_bit_cast(u16, by) << 16);
}

// packed A-fragment (W^T) layout, per layer: idx = ((s*4 + m)*64 + lane)*8 + j
// value = W[k][16*m + (lane&15)], k = s*32 + (lane>>4)*8 + j
#define PK_EW1 0
#define PK_EW2 12288
#define PK_EW3 16384
#define PK_NW1 20480
#define PK_NW2 28672
#define PK_NW3 32768
#define PK_TOTAL 36864
#define EW_U16 20480
#define TLOOP 20

__global__ void pack_weights_kernel(const float* __restrict__ eW1, const float* __restrict__ eW2,
                                    const float* __restrict__ eW3, const float* __restrict__ nW1,
                                    const float* __restrict__ nW2, const float* __restrict__ nW3,
                                    u16* __restrict__ P) {
    int idx = blockIdx.x * blockDim.x + threadIdx.x;
    if (idx >= PK_TOTAL) return;
    const float* W; int base;
    if (idx < PK_EW2)      { W = eW1; base = PK_EW1; }
    else if (idx < PK_EW3) { W = eW2; base = PK_EW2; }
    else if (idx < PK_NW1) { W = eW3; base = PK_EW3; }
    else if (idx < PK_NW2) { W = nW1; base = PK_NW1; }
    else if (idx < PK_NW3) { W = nW2; base = PK_NW2; }
    else                   { W = nW3; base = PK_NW3; }
    int r = idx - base;
    int j = r & 7, lane = (r >> 3) & 63, m = (r >> 9) & 3, s = r >> 11;
    int k = s * 32 + (lane >> 4) * 8 + j;
    int col = 16 * m + (lane & 15);
    P[idx] = f2bf(W[k * 64 + col]);
}

// ---------------- CSR build ----------------
__global__ void degree_kernel(const int* __restrict__ edge_idx, int* __restrict__ deg, int E) {
    int e = blockIdx.x * blockDim.x + threadIdx.x;
    if (e < E) atomicAdd(&deg[edge_idx[2 * e]], 1);
}

__global__ void scan_blocks_kernel(const int* __restrict__ deg, int* __restrict__ off,
                                   int* __restrict__ partials, int N) {
    __shared__ int sh[256];
    const int t = threadIdx.x;
    const int g = blockIdx.x * 256 + t;
    int v = (g < N) ? deg[g] : 0;
    sh[t] = v;
    __syncthreads();
#pragma unroll
    for (int d = 1; d < 256; d <<= 1) {
        int add = (t >= d) ? sh[t - d] : 0;
        __syncthreads();
        sh[t] += add;
        __syncthreads();
    }
    if (g < N) off[g] = sh[t] - v;
    if (t == 255) partials[blockIdx.x] = sh[255];
}

__global__ void scan_partials_kernel(int* __restrict__ partials, int nparts) {
    __shared__ int sh[256];
    const int t = threadIdx.x;
    int v = (t < nparts) ? partials[t] : 0;
    sh[t] = v;
    __syncthreads();
#pragma unroll
    for (int d = 1; d < 256; d <<= 1) {
        int add = (t >= d) ? sh[t - d] : 0;
        __syncthreads();
        sh[t] += add;
        __syncthreads();
    }
    if (t < nparts) partials[t] = sh[t] - v;
}

__global__ void finalize_offsets_kernel(int* __restrict__ off, int* __restrict__ pos,
                                        const int* __restrict__ partials, int N, int E) {
    int g = blockIdx.x * blockDim.x + threadIdx.x;
    if (g < N) {
        int o = off[g] + partials[g >> 8];
        off[g] = o;
        pos[g] = o;
    }
    if (g == 0) off[N] = E;
}

__global__ void fill_csr_kernel(const int* __restrict__ edge_idx, int* __restrict__ pos,
                                int* __restrict__ csr, int E) {
    int e = blockIdx.x * blockDim.x + threadIdx.x;
    if (e < E) {
        int slot = atomicAdd(&pos[edge_idx[2 * e]], 1);
        csr[slot] = e;
    }
}

// ---------------- gather (fp32 out_edge, csr-indexed) — R7's proven kernel ----------------
__global__ __launch_bounds__(256) void gather_csr_kernel(
    const float* __restrict__ proc_edge, const int* __restrict__ off,
    const int* __restrict__ csr, u16* __restrict__ nodal16, int N)
{
    const int wid = threadIdx.x >> 6, lane = threadIdx.x & 63;
    const int n = blockIdx.x * 4 + wid;
    if (n >= N) return;
    const int r = lane >> 4;
    const int q = lane & 15;
    const int beg = off[n], end = off[n + 1];
    f32x4 v0 = 0.0f, v1 = 0.0f, v2 = 0.0f, v3 = 0.0f;
    int j = beg + r;
    for (; j + 12 < end; j += 16) {
        int e0 = csr[j], e1 = csr[j + 4], e2 = csr[j + 8], e3 = csr[j + 12];
        v0 += *(const f32x4*)(proc_edge + (size_t)e0 * 64 + q * 4);
        v1 += *(const f32x4*)(proc_edge + (size_t)e1 * 64 + q * 4);
        v2 += *(const f32x4*)(proc_edge + (size_t)e2 * 64 + q * 4);
        v3 += *(const f32x4*)(proc_edge + (size_t)e3 * 64 + q * 4);
    }
    for (; j < end; j += 4) {
        int e0 = csr[j];
        v0 += *(const f32x4*)(proc_edge + (size_t)e0 * 64 + q * 4);
    }
    v0 += v1; v2 += v3; v0 += v2;
#pragma unroll
    for (int i = 0; i < 4; ++i) {
        v0[i] += __shfl_xor(v0[i], 16, 64);
        v0[i] += __shfl_xor(v0[i], 32, 64);
    }
    if (r == 0) {
        u32x2 pv; pv[0] = pk2(v0[0], v0[1]); pv[1] = pk2(v0[2], v0[3]);
        *(u32x2*)(nodal16 + (size_t)n * 64 + q * 4) = pv;
    }
}

// ---------------- edge MLP + LN: tile loop, double-buffered gll staging, counted vmcnt ----------------
__global__ __launch_bounds__(256) void edge_mlp_kernel(
    const float* __restrict__ node_feat, const float* __restrict__ edge_feat,
    const int* __restrict__ edge_idx, const u16* __restrict__ Pw,
    const float* __restrict__ b1g, const float* __restrict__ b2g, const float* __restrict__ b3g,
    const float* __restrict__ gg, const float* __restrict__ betag,
    float* __restrict__ out_edge, int E, int ntiles)
{
    __shared__ u16 wlds[EW_U16];        // 40 KB: EW1 | EW2 | EW3, resident whole kernel
    __shared__ u16 stage[2][4][6144];   // double-buffered 12 KB per wave
    __shared__ float params[5][64];
    const int tid = threadIdx.x;
#pragma unroll
    for (int i = 0; i < 10; ++i) {
        int idx = i * 256 + tid;
        *(u32x4*)(wlds + (size_t)idx * 8) = *(const u32x4*)(Pw + (size_t)idx * 8);
    }
    if (tid < 64) {
        params[0][tid] = b1g[tid];
        params[1][tid] = b2g[tid];
        params[2][tid] = b3g[tid];
        params[3][tid] = gg[tid];
        params[4][tid] = betag[tid];
    }
    __syncthreads();

    const int wid = tid >> 6, lane = tid & 63;
    const int er = lane & 15, a = lane >> 4;
    const int tile0 = blockIdx.x * TLOOP;
    if (tile0 >= ntiles) return;
    const int eoff = wid * 16 + er;     // this lane's edge slot within a tile
    const int swz = (er & 7) << 4;

    // issue the 12 async 1KB chunk loads of one tile into a wave's stage slot
    auto issue_stage = [&](u16* dst, int e_, int cn_, int sn_) {
#pragma unroll
        for (int s = 0; s < 6; ++s) {
            const float* base;
            if (s < 2)      base = edge_feat + (size_t)e_ * 64 + s * 32 + a * 8;
            else if (s < 4) base = node_feat + (size_t)cn_ * 64 + (s - 2) * 32 + a * 8;
            else            base = node_feat + (size_t)sn_ * 64 + (s - 4) * 32 + a * 8;
            __builtin_amdgcn_global_load_lds(
                (const __attribute__((address_space(1))) void*)base,
                (__attribute__((address_space(3))) void*)(dst + (2 * s) * 512), 16, 0, 0);
            __builtin_amdgcn_global_load_lds(
                (const __attribute__((address_space(1))) void*)(base + 4),
                (__attribute__((address_space(3))) void*)(dst + (2 * s + 1) * 512), 16, 0, 0);
        }
    };
    auto clampe = [&](int t) {
        long long e = (long long)(tile0 + t) * 64 + eoff;
        return (int)((e < E) ? e : (E - 1));
    };

    // prologue: stage tile 0; prefetch tile 1's indices
    int ec0 = clampe(0);
    int2 ii0 = *(const int2*)(edge_idx + 2 * ec0);
    issue_stage(stage[0][wid], ec0, ii0.x, ii0.y);
    int ecn = clampe(1);
    int2 iin = *(const int2*)(edge_idx + 2 * ecn);

    for (int t = 0; t < TLOOP; ++t) {
        u16* cur = stage[t & 1][wid];
        u16* nxt = stage[(t & 1) ^ 1][wid];
        // stage tile t+1 (always; clamped tail loads are harmless)
        issue_stage(nxt, ecn, iin.x, iin.y);
        // prefetch tile t+2's indices (overlaps compute)
        int ec2 = clampe(t + 2);
        int2 ii2 = *(const int2*)(edge_idx + 2 * ec2);
        // wait for tile t's 12 loads (+ earlier stores); leaves the new 12+idx in flight
        __builtin_amdgcn_sched_barrier(0);
        asm volatile("s_waitcnt vmcnt(13)" ::: "memory");
        __builtin_amdgcn_sched_barrier(0);

        // ---- layer 1: K = 192 from staged chunks (lane*16B)
        f32x4 acc[4];
#pragma unroll
        for (int m = 0; m < 4; ++m) acc[m] = 0.0f;
#pragma unroll
        for (int s = 0; s < 6; ++s) {
            f32x4 lo = *(const f32x4*)((const char*)cur + (2 * s) * 1024 + lane * 16);
            f32x4 hi = *(const f32x4*)((const char*)cur + (2 * s + 1) * 1024 + lane * 16);
            bf16x8 bf = cvt2bf(lo, hi);
#pragma unroll
            for (int m = 0; m < 4; ++m) {
                bf16x8 af = *(const bf16x8*)(wlds + PK_EW1 + ((s * 4 + m) * 64 + lane) * 8);
                acc[m] = __builtin_amdgcn_mfma_f32_16x16x32_bf16(af, bf, acc[m], 0, 0, 0);
            }
        }

        // ---- layers 2 & 3 (htile = first 2KB of cur, XOR-swizzled; same-wave DS in-order)
        u16* ht = cur;
#pragma unroll
        for (int m = 0; m < 4; ++m) {
            float v0 = fmaxf(acc[m][0] + params[0][16 * m + 4 * a + 0], 0.0f);
            float v1 = fmaxf(acc[m][1] + params[0][16 * m + 4 * a + 1], 0.0f);
            float v2 = fmaxf(acc[m][2] + params[0][16 * m + 4 * a + 2], 0.0f);
            float v3 = fmaxf(acc[m][3] + params[0][16 * m + 4 * a + 3], 0.0f);
            u32x2 pv; pv[0] = pk2(v0, v1); pv[1] = pk2(v2, v3);
            int boff = (er * 128 + (16 * m + 4 * a) * 2) ^ swz;
            *(u32x2*)((char*)ht + boff) = pv;
        }
        f32x4 a2[4];
#pragma unroll
        for (int m = 0; m < 4; ++m) a2[m] = 0.0f;
#pragma unroll
        for (int s = 0; s < 2; ++s) {
            int boff = (er * 128 + s * 64 + a * 16) ^ swz;
            bf16x8 bf = *(const bf16x8*)((char*)ht + boff);
#pragma unroll
            for (int m = 0; m < 4; ++m) {
                bf16x8 af = *(const bf16x8*)(wlds + PK_EW2 + ((s * 4 + m) * 64 + lane) * 8);
                a2[m] = __builtin_amdgcn_mfma_f32_16x16x32_bf16(af, bf, a2[m], 0, 0, 0);
            }
        }
#pragma unroll
        for (int m = 0; m < 4; ++m) {
            float v0 = fmaxf(a2[m][0] + params[1][16 * m + 4 * a + 0], 0.0f);
            float v1 = fmaxf(a2[m][1] + params[1][16 * m + 4 * a + 1], 0.0f);
            float v2 = fmaxf(a2[m][2] + params[1][16 * m + 4 * a + 2], 0.0f);
            float v3 = fmaxf(a2[m][3] + params[1][16 * m + 4 * a + 3], 0.0f);
            u32x2 pv; pv[0] = pk2(v0, v1); pv[1] = pk2(v2, v3);
            int boff = (er * 128 + (16 * m + 4 * a) * 2) ^ swz;
            *(u32x2*)((char*)ht + boff) = pv;
        }
        f32x4 a3[4];
#pragma unroll
        for (int m = 0; m < 4; ++m) a3[m] = 0.0f;
#pragma unroll
        for (int s = 0; s < 2; ++s) {
            int boff = (er * 128 + s * 64 + a * 16) ^ swz;
            bf16x8 bf = *(const bf16x8*)((char*)ht + boff);
#pragma unroll
            for (int m = 0; m < 4; ++m) {
                bf16x8 af = *(const bf16x8*)(wlds + PK_EW3 + ((s * 4 + m) * 64 + lane) * 8);
                a3[m] = __builtin_amdgcn_mfma_f32_16x16x32_bf16(af, bf, a3[m], 0, 0, 0);
            }
        }
        // LayerNorm + store
        float vals[16], sum = 0.0f, ssq = 0.0f;
#pragma unroll
        for (int m = 0; m < 4; ++m)
#pragma unroll
            for (int r = 0; r < 4; ++r) {
                float v = a3[m][r] + params[2][16 * m + 4 * a + r];
                vals[4 * m + r] = v; sum += v; ssq += v * v;
            }
        sum += __shfl_xor(sum, 16, 64); sum += __shfl_xor(sum, 32, 64);
        ssq += __shfl_xor(ssq, 16, 64); ssq += __shfl_xor(ssq, 32, 64);
        const float mean = sum * 0.015625f;
        const float var = ssq * 0.015625f - mean * mean;
        const float inv = rsqrtf(var + 1e-5f);
        const long long eg = (long long)(tile0 + t) * 64 + eoff;
        if (eg < E) {
#pragma unroll
            for (int m = 0; m < 4; ++m) {
                f32x4 o;
#pragma unroll
                for (int r = 0; r < 4; ++r) {
                    int f = 16 * m + 4 * a + r;
                    o[r] = (vals[4 * m + r] - mean) * inv * params[3][f] + params[4][f];
                }
                *(f32x4*)(out_edge + (size_t)eg * 64 + 16 * m + 4 * a) = o;
            }
        }
        // rotate prefetched indices
        ecn = ec2; iin = ii2;
    }
}

// ---------------- node MLP + LN (nodal16 bf16; linear reads) — R7 verbatim ----------------
__global__ __launch_bounds__(256) void node_mlp_kernel(
    const float* __restrict__ node_feat, const u16* __restrict__ nodal16,
    const u16* __restrict__ Pw,
    const float* __restrict__ b1g, const float* __restrict__ b2g, const float* __restrict__ b3g,
    const float* __restrict__ gg, const float* __restrict__ betag,
    float* __restrict__ out_node, int N)
{
    __shared__ float params[5][64];
    __shared__ u16 htile[4][1024];
    const int tid = threadIdx.x;
    if (tid < 64) {
        params[0][tid] = b1g[tid];
        params[1][tid] = b2g[tid];
        params[2][tid] = b3g[tid];
        params[3][tid] = gg[tid];
        params[4][tid] = betag[tid];
    }
    __syncthreads();
    const int wid = tid >> 6, lane = tid & 63;
    const int er = lane & 15, a = lane >> 4;
    const int nbase = (blockIdx.x * 4 + wid) * 16;
    if (nbase >= N) return;
    const int n = nbase + er;
    u16* ht = htile[wid];
    const int swz = (er & 7) << 4;

    f32x4 acc[4];
#pragma unroll
    for (int m = 0; m < 4; ++m) acc[m] = 0.0f;

#pragma unroll
    for (int s = 0; s < 4; ++s) {
        bf16x8 af[4];
#pragma unroll
        for (int m = 0; m < 4; ++m)
            af[m] = *(const bf16x8*)(Pw + PK_NW1 + ((s * 4 + m) * 64 + lane) * 8);
        bf16x8 bf;
        if (s < 2) bf = load8f_bf(node_feat + (size_t)n * 64 + s * 32 + a * 8);
        else       bf = *(const bf16x8*)(nodal16 + (size_t)n * 64 + (s - 2) * 32 + a * 8);
#pragma unroll
        for (int m = 0; m < 4; ++m)
            acc[m] = __builtin_amdgcn_mfma_f32_16x16x32_bf16(af[m], bf, acc[m], 0, 0, 0);
    }
#pragma unroll
    for (int m = 0; m < 4; ++m) {
        float v0 = fmaxf(acc[m][0] + params[0][16 * m + 4 * a + 0], 0.0f);
        float v1 = fmaxf(acc[m][1] + params[0][16 * m + 4 * a + 1], 0.0f);
        float v2 = fmaxf(acc[m][2] + params[0][16 * m + 4 * a + 2], 0.0f);
        float v3 = fmaxf(acc[m][3] + params[0][16 * m + 4 * a + 3], 0.0f);
        u32x2 pv; pv[0] = pk2(v0, v1); pv[1] = pk2(v2, v3);
        int boff = (er * 128 + (16 * m + 4 * a) * 2) ^ swz;
        *(u32x2*)((char*)ht + boff) = pv;
    }

#pragma unroll
    for (int m = 0; m < 4; ++m) acc[m] = 0.0f;
#pragma unroll
    for (int s = 0; s < 2; ++s) {
        bf16x8 af[4];
#pragma unroll
        for (int m = 0; m < 4; ++m)
            af[m] = *(const bf16x8*)(Pw + PK_NW2 + ((s * 4 + m) * 64 + lane) * 8);
        int boff = (er * 128 + s * 64 + a * 16) ^ swz;
        bf16x8 bf = *(const bf16x8*)((char*)ht + boff);
#pragma unroll
        for (int m = 0; m < 4; ++m)
            acc[m] = __builtin_amdgcn_mfma_f32_16x16x32_bf16(af[m], bf, acc[m], 0, 0, 0);
    }
#pragma unroll
    for (int m = 0; m < 4; ++m) {
        float v0 = fmaxf(acc[m][0] + params[1][16 * m + 4 * a + 0], 0.0f);
        float v1 = fmaxf(acc[m][1] + params[1][16 * m + 4 * a + 1], 0.0f);
        float v2 = fmaxf(acc[m][2] + params[1][16 * m + 4 * a + 2], 0.0f);
        float v3 = fmaxf(acc[m][3] + params[1][16 * m + 4 * a + 3], 0.0f);
        u32x2 pv; pv[0] = pk2(v0, v1); pv[1] = pk2(v2, v3);
        int boff = (er * 128 + (16 * m + 4 * a) * 2) ^ swz;
        *(u32x2*)((char*)ht + boff) = pv;
    }

#pragma unroll
    for (int m = 0; m < 4; ++m) acc[m] = 0.0f;
#pragma unroll
    for (int s = 0; s < 2; ++s) {
        bf16x8 af[4];
#pragma unroll
        for (int m = 0; m < 4; ++m)
            af[m] = *(const bf16x8*)(Pw + PK_NW3 + ((s * 4 + m) * 64 + lane) * 8);
        int boff = (er * 128 + s * 64 + a * 16) ^ swz;
        bf16x8 bf = *(const bf16x8*)((char*)ht + boff);
#pragma unroll
        for (int m = 0; m < 4; ++m)
            acc[m] = __builtin_amdgcn_mfma_f32_16x16x32_bf16(af[m], bf, acc[m], 0, 0, 0);
    }
    float vals[16], sum = 0.0f, ssq = 0.0f;
#pragma unroll
    for (int m = 0; m < 4; ++m)
#pragma unroll
        for (int r = 0; r < 4; ++r) {
            float v = acc[m][r] + params[2][16 * m + 4 * a + r];
            vals[4 * m + r] = v; sum += v; ssq += v * v;
        }
    sum += __shfl_xor(sum, 16, 64); sum += __shfl_xor(sum, 32, 64);
    ssq += __shfl_xor(ssq, 16, 64); ssq += __shfl_xor(ssq, 32, 64);
    const float mean = sum * 0.015625f;
    const float var = ssq * 0.015625f - mean * mean;
    const float inv = rsqrtf(var + 1e-5f);
#pragma unroll
    for (int m = 0; m < 4; ++m) {
        f32x4 o;
#pragma unroll
        for (int r = 0; r < 4; ++r) {
            int f = 16 * m + 4 * a + r;
            o[r] = (vals[4 * m + r] - mean) * inv * params[3][f] + params[4][f];
        }
        *(f32x4*)(out_node + (size_t)n * 64 + 16 * m + 4 * a) = o;
    }
}

extern "C" void kernel_launch(void* const* d_in, const int* in_sizes, int n_in,
                              void* d_out, int out_size, void* d_ws, size_t ws_size,
                              hipStream_t stream) {
    const float* node_feat = (const float*)d_in[0];
    const float* edge_feat = (const float*)d_in[1];
    const int* edge_idx  = (const int*)d_in[2];
    const float* eW1 = (const float*)d_in[4];
    const float* eb1 = (const float*)d_in[5];
    const float* eW2 = (const float*)d_in[6];
    const float* eb2 = (const float*)d_in[7];
    const float* eW3 = (const float*)d_in[8];
    const float* eb3 = (const float*)d_in[9];
    const float* eg  = (const float*)d_in[10];
    const float* ebt = (const float*)d_in[11];
    const float* nW1 = (const float*)d_in[12];
    const float* nb1 = (const float*)d_in[13];
    const float* nW2 = (const float*)d_in[14];
    const float* nb2 = (const float*)d_in[15];
    const float* nW3 = (const float*)d_in[16];
    const float* nb3 = (const float*)d_in[17];
    const float* ng  = (const float*)d_in[18];
    const float* nbt = (const float*)d_in[19];

    const int N = in_sizes[0] / 64;
    const int E = in_sizes[1] / 64;
    const int nparts = (N + 255) / 256;

    // ws layout
    char* w = (char*)d_ws;
    int* off      = (int*)w;                    w += (size_t)(N + 1) * 4;
    int* pos      = (int*)w;                    w += (size_t)N * 4;
    int* partials = (int*)w;                    w += 256 * 4;
    int* csr      = (int*)w;                    w += (size_t)E * 4;
    u16* Pw       = (u16*)w;                    w += (size_t)PK_TOTAL * 2;
    w = (char*)(((size_t)w + 255) & ~(size_t)255);
    u16* nodal16  = (u16*)w;                    // N*64 bf16

    float* out_edge = (float*)d_out;
    float* out_node = out_edge + (size_t)E * 64;

    pack_weights_kernel<<<(PK_TOTAL + 255) / 256, 256, 0, stream>>>(eW1, eW2, eW3, nW1, nW2, nW3, Pw);

    // edge MLP: pipelined tile loop (TLOOP tiles of 64 edges per block)
    const int ntiles = (E + 63) / 64;
    const int eblocks = (ntiles + TLOOP - 1) / TLOOP;
    edge_mlp_kernel<<<eblocks, 256, 0, stream>>>(node_feat, edge_feat, edge_idx, Pw,
                                                 eb1, eb2, eb3, eg, ebt, out_edge, E, ntiles);

    // CSR build (pos doubles as degree histogram)
    hipMemsetAsync(pos, 0, (size_t)N * 4, stream);
    degree_kernel<<<(E + 255) / 256, 256, 0, stream>>>(edge_idx, pos, E);
    scan_blocks_kernel<<<nparts, 256, 0, stream>>>(pos, off, partials, N);
    scan_partials_kernel<<<1, 256, 0, stream>>>(partials, nparts);
    finalize_offsets_kernel<<<(N + 255) / 256, 256, 0, stream>>>(off, pos, partials, N, E);
    fill_csr_kernel<<<(E + 255) / 256, 256, 0, stream>>>(edge_idx, pos, csr, E);

    // segment-sum gather (fp32 rows -> bf16 nodal)
    gather_csr_kernel<<<(N + 3) / 4, 256, 0, stream>>>(out_edge, off, csr, nodal16, N);

    const int nblocks = (N + 63) / 64;
    node_mlp_kernel<<<nblocks, 256, 0, stream>>>(node_feat, nodal16, Pw,
                                                 nb1, nb2, nb3, ng, nbt, out_node, N);
}

// Round 14
// 597.291 us; speedup vs baseline: 1.0960x; 1.0674x over previous
//
#include <hip/hip_runtime.h>

typedef unsigned short u16;
typedef unsigned int u32;
typedef __attribute__((ext_vector_type(8))) __bf16 bf16x8;
typedef __attribute__((ext_vector_type(4))) float f32x4;
typedef __attribute__((ext_vector_type(2))) u32 u32x2;
typedef __attribute__((ext_vector_type(4))) u32 u32x4;

__device__ __forceinline__ u16 f2bf(float f) {
    u32 u = __float_as_uint(f);
    u = (u + 0x7FFFu + ((u >> 16) & 1u)) >> 16;
    return (u16)u;
}
__device__ __forceinline__ bf16x8 cvt2bf(f32x4 lo, f32x4 hi) {
    bf16x8 r;
    r[0] = (__bf16)lo[0]; r[1] = (__bf16)lo[1]; r[2] = (__bf16)lo[2]; r[3] = (__bf16)lo[3];
    r[4] = (__bf16)hi[0]; r[5] = (__bf16)hi[1]; r[6] = (__bf16)hi[2]; r[7] = (__bf16)hi[3];
    return r;
}
__device__ __forceinline__ bf16x8 load8f_bf(const float* p) {
    return cvt2bf(*(const f32x4*)p, *(const f32x4*)(p + 4));
}
__device__ __forceinline__ u32 pk2(float x, float y) {
    __bf16 bx = (__bf16)x, by = (__bf16)y;
    return (u32)__builtin_bit_cast(u16, bx) | ((u32)__builtin_bit_cast(u16, by) << 16);
}

// packed A-fragment (W^T) layout, per layer: idx = ((s*4 + m)*64 + lane)*8 + j
// value = W[k][16*m + (lane&15)], k = s*32 + (lane>>4)*8 + j
#define PK_EW1 0
#define PK_EW2 12288
#define PK_EW3 16384
#define PK_NW1 20480
#define PK_NW2 28672
#define PK_NW3 32768
#define PK_TOTAL 36864

__global__ void pack_weights_kernel(const float* __restrict__ eW1, const float* __restrict__ eW2,
                                    const float* __restrict__ eW3, const float* __restrict__ nW1,
                                    const float* __restrict__ nW2, const float* __restrict__ nW3,
                                    u16* __restrict__ P) {
    int idx = blockIdx.x * blockDim.x + threadIdx.x;
    if (idx >= PK_TOTAL) return;
    const float* W; int base;
    if (idx < PK_EW2)      { W = eW1; base = PK_EW1; }
    else if (idx < PK_EW3) { W = eW2; base = PK_EW2; }
    else if (idx < PK_NW1) { W = eW3; base = PK_EW3; }
    else if (idx < PK_NW2) { W = nW1; base = PK_NW1; }
    else if (idx < PK_NW3) { W = nW2; base = PK_NW2; }
    else                   { W = nW3; base = PK_NW3; }
    int r = idx - base;
    int j = r & 7, lane = (r >> 3) & 63, m = (r >> 9) & 3, s = r >> 11;
    int k = s * 32 + (lane >> 4) * 8 + j;
    int col = 16 * m + (lane & 15);
    P[idx] = f2bf(W[k * 64 + col]);
}

// ---------------- CSR build ----------------
__global__ void degree_kernel(const int* __restrict__ edge_idx, int* __restrict__ deg, int E) {
    int e = blockIdx.x * blockDim.x + threadIdx.x;
    if (e < E) atomicAdd(&deg[edge_idx[2 * e]], 1);
}

__global__ void scan_blocks_kernel(const int* __restrict__ deg, int* __restrict__ off,
                                   int* __restrict__ partials, int N) {
    __shared__ int sh[256];
    const int t = threadIdx.x;
    const int g = blockIdx.x * 256 + t;
    int v = (g < N) ? deg[g] : 0;
    sh[t] = v;
    __syncthreads();
#pragma unroll
    for (int d = 1; d < 256; d <<= 1) {
        int add = (t >= d) ? sh[t - d] : 0;
        __syncthreads();
        sh[t] += add;
        __syncthreads();
    }
    if (g < N) off[g] = sh[t] - v;
    if (t == 255) partials[blockIdx.x] = sh[255];
}

__global__ void scan_partials_kernel(int* __restrict__ partials, int nparts) {
    __shared__ int sh[256];
    const int t = threadIdx.x;
    int v = (t < nparts) ? partials[t] : 0;
    sh[t] = v;
    __syncthreads();
#pragma unroll
    for (int d = 1; d < 256; d <<= 1) {
        int add = (t >= d) ? sh[t - d] : 0;
        __syncthreads();
        sh[t] += add;
        __syncthreads();
    }
    if (t < nparts) partials[t] = sh[t] - v;
}

__global__ void finalize_offsets_kernel(int* __restrict__ off, int* __restrict__ pos,
                                        const int* __restrict__ partials, int N, int E) {
    int g = blockIdx.x * blockDim.x + threadIdx.x;
    if (g < N) {
        int o = off[g] + partials[g >> 8];
        off[g] = o;
        pos[g] = o;
    }
    if (g == 0) off[N] = E;
}

__global__ void fill_csr_kernel(const int* __restrict__ edge_idx, int* __restrict__ pos,
                                int* __restrict__ csr, int E) {
    int e = blockIdx.x * blockDim.x + threadIdx.x;
    if (e < E) {
        int slot = atomicAdd(&pos[edge_idx[2 * e]], 1);
        csr[slot] = e;
    }
}

// ---------------- gather (fp32 out_edge, csr-indexed) — R7's proven kernel ----------------
__global__ __launch_bounds__(256) void gather_csr_kernel(
    const float* __restrict__ proc_edge, const int* __restrict__ off,
    const int* __restrict__ csr, u16* __restrict__ nodal16, int N)
{
    const int wid = threadIdx.x >> 6, lane = threadIdx.x & 63;
    const int n = blockIdx.x * 4 + wid;
    if (n >= N) return;
    const int r = lane >> 4;
    const int q = lane & 15;
    const int beg = off[n], end = off[n + 1];
    f32x4 v0 = 0.0f, v1 = 0.0f, v2 = 0.0f, v3 = 0.0f;
    int j = beg + r;
    for (; j + 12 < end; j += 16) {
        int e0 = csr[j], e1 = csr[j + 4], e2 = csr[j + 8], e3 = csr[j + 12];
        v0 += *(const f32x4*)(proc_edge + (size_t)e0 * 64 + q * 4);
        v1 += *(const f32x4*)(proc_edge + (size_t)e1 * 64 + q * 4);
        v2 += *(const f32x4*)(proc_edge + (size_t)e2 * 64 + q * 4);
        v3 += *(const f32x4*)(proc_edge + (size_t)e3 * 64 + q * 4);
    }
    for (; j < end; j += 4) {
        int e0 = csr[j];
        v0 += *(const f32x4*)(proc_edge + (size_t)e0 * 64 + q * 4);
    }
    v0 += v1; v2 += v3; v0 += v2;
#pragma unroll
    for (int i = 0; i < 4; ++i) {
        v0[i] += __shfl_xor(v0[i], 16, 64);
        v0[i] += __shfl_xor(v0[i], 32, 64);
    }
    if (r == 0) {
        u32x2 pv; pv[0] = pk2(v0[0], v0[1]); pv[1] = pk2(v0[2], v0[3]);
        *(u32x2*)(nodal16 + (size_t)n * 64 + q * 4) = pv;
    }
}

// ---------------- edge MLP + LN: R7 structure, ET=4, s-outer layer-1 (A-frag reuse) ----------------
#define ET 4
__global__ __launch_bounds__(512, 4) void edge_mlp_kernel(
    const float* __restrict__ node_feat, const float* __restrict__ edge_feat,
    const int* __restrict__ edge_idx, const u16* __restrict__ Pw,
    const float* __restrict__ b1g, const float* __restrict__ b2g, const float* __restrict__ b3g,
    const float* __restrict__ gg, const float* __restrict__ betag,
    float* __restrict__ out_edge, int E)
{
    __shared__ u16 wlds[12288];     // 24 KB: phase A = EW1; phase B = EW2|EW3
    __shared__ u16 htile[8][1024];  // per-wave 16x64 bf16 tile, XOR-swizzled, reused per subtile
    __shared__ float params[5][64];
    const int tid = threadIdx.x;
    // ---- stage layer-1 weights (24 KB)
#pragma unroll
    for (int i = 0; i < 3; ++i) {
        int idx = i * 512 + tid;
        *(u32x4*)(wlds + (size_t)idx * 8) = *(const u32x4*)(Pw + PK_EW1 + (size_t)idx * 8);
    }
    if (tid < 64) {
        params[0][tid] = b1g[tid];
        params[1][tid] = b2g[tid];
        params[2][tid] = b3g[tid];
        params[3][tid] = gg[tid];
        params[4][tid] = betag[tid];
    }
    __syncthreads();

    const int wid = tid >> 6, lane = tid & 63;
    const int er = lane & 15, a = lane >> 4;
    const int ebase = (blockIdx.x * 8 + wid) * (16 * ET);
    u16* ht = htile[wid];
    const int swz = (er & 7) << 4;

    int eidx[ET], cn[ET], sn[ET];
#pragma unroll
    for (int t = 0; t < ET; ++t) {
        int e = ebase + t * 16 + er;
        if (e > E - 1) e = E - 1;
        eidx[t] = e;
        int2 ii = *(const int2*)(edge_idx + 2 * e);
        cn[t] = ii.x; sn[t] = ii.y;
    }

    f32x4 acc[ET][4];
#pragma unroll
    for (int t = 0; t < ET; ++t)
#pragma unroll
        for (int m = 0; m < 4; ++m) acc[t][m] = 0.0f;

    // ---- layer 1: K = 192, s-outer — A-fragments loaded ONCE per s, reused across 4 subtiles
#pragma unroll
    for (int s = 0; s < 6; ++s) {
        bf16x8 af[4];
#pragma unroll
        for (int m = 0; m < 4; ++m)
            af[m] = *(const bf16x8*)(wlds + ((s * 4 + m) * 64 + lane) * 8);
#pragma unroll
        for (int t = 0; t < ET; ++t) {
            const float* src;
            if (s < 2)      src = edge_feat + (size_t)eidx[t] * 64 + s * 32 + a * 8;
            else if (s < 4) src = node_feat + (size_t)cn[t] * 64 + (s - 2) * 32 + a * 8;
            else            src = node_feat + (size_t)sn[t] * 64 + (s - 4) * 32 + a * 8;
            f32x4 lo = *(const f32x4*)src;
            f32x4 hi = *(const f32x4*)(src + 4);
            bf16x8 bf = cvt2bf(lo, hi);
#pragma unroll
            for (int m = 0; m < 4; ++m)
                acc[t][m] = __builtin_amdgcn_mfma_f32_16x16x32_bf16(af[m], bf, acc[t][m], 0, 0, 0);
        }
    }
    __syncthreads();   // everyone done with layer-1 weights
    // ---- re-stage: EW2 | EW3 (16 KB) into the same buffer
#pragma unroll
    for (int i = 0; i < 2; ++i) {
        int idx = i * 512 + tid;
        *(u32x4*)(wlds + (size_t)idx * 8) = *(const u32x4*)(Pw + PK_EW2 + (size_t)idx * 8);
    }
    __syncthreads();

    // ---- layers 2 & 3 per subtile (weights from LDS: L2 at 0, L3 at 4096) — R7 verbatim body
#pragma unroll
    for (int t = 0; t < ET; ++t) {
        // bias + relu (layer1) -> tile
#pragma unroll
        for (int m = 0; m < 4; ++m) {
            float v0 = fmaxf(acc[t][m][0] + params[0][16 * m + 4 * a + 0], 0.0f);
            float v1 = fmaxf(acc[t][m][1] + params[0][16 * m + 4 * a + 1], 0.0f);
            float v2 = fmaxf(acc[t][m][2] + params[0][16 * m + 4 * a + 2], 0.0f);
            float v3 = fmaxf(acc[t][m][3] + params[0][16 * m + 4 * a + 3], 0.0f);
            u32x2 pv; pv[0] = pk2(v0, v1); pv[1] = pk2(v2, v3);
            int boff = (er * 128 + (16 * m + 4 * a) * 2) ^ swz;
            *(u32x2*)((char*)ht + boff) = pv;
        }
        // layer 2: K = 64
        f32x4 a2[4];
#pragma unroll
        for (int m = 0; m < 4; ++m) a2[m] = 0.0f;
#pragma unroll
        for (int s = 0; s < 2; ++s) {
            int boff = (er * 128 + s * 64 + a * 16) ^ swz;
            bf16x8 bf = *(const bf16x8*)((char*)ht + boff);
#pragma unroll
            for (int m = 0; m < 4; ++m) {
                bf16x8 af = *(const bf16x8*)(wlds + ((s * 4 + m) * 64 + lane) * 8);
                a2[m] = __builtin_amdgcn_mfma_f32_16x16x32_bf16(af, bf, a2[m], 0, 0, 0);
            }
        }
        // bias + relu (layer2) -> tile (same-wave DS ops are in-order)
#pragma unroll
        for (int m = 0; m < 4; ++m) {
            float v0 = fmaxf(a2[m][0] + params[1][16 * m + 4 * a + 0], 0.0f);
            float v1 = fmaxf(a2[m][1] + params[1][16 * m + 4 * a + 1], 0.0f);
            float v2 = fmaxf(a2[m][2] + params[1][16 * m + 4 * a + 2], 0.0f);
            float v3 = fmaxf(a2[m][3] + params[1][16 * m + 4 * a + 3], 0.0f);
            u32x2 pv; pv[0] = pk2(v0, v1); pv[1] = pk2(v2, v3);
            int boff = (er * 128 + (16 * m + 4 * a) * 2) ^ swz;
            *(u32x2*)((char*)ht + boff) = pv;
        }
        // layer 3: K = 64 (no relu)
        f32x4 a3[4];
#pragma unroll
        for (int m = 0; m < 4; ++m) a3[m] = 0.0f;
#pragma unroll
        for (int s = 0; s < 2; ++s) {
            int boff = (er * 128 + s * 64 + a * 16) ^ swz;
            bf16x8 bf = *(const bf16x8*)((char*)ht + boff);
#pragma unroll
            for (int m = 0; m < 4; ++m) {
                bf16x8 af = *(const bf16x8*)(wlds + 4096 + ((s * 4 + m) * 64 + lane) * 8);
                a3[m] = __builtin_amdgcn_mfma_f32_16x16x32_bf16(af, bf, a3[m], 0, 0, 0);
            }
        }
        // LayerNorm + store
        float vals[16], sum = 0.0f, ssq = 0.0f;
#pragma unroll
        for (int m = 0; m < 4; ++m)
#pragma unroll
            for (int r = 0; r < 4; ++r) {
                float v = a3[m][r] + params[2][16 * m + 4 * a + r];
                vals[4 * m + r] = v; sum += v; ssq += v * v;
            }
        sum += __shfl_xor(sum, 16, 64); sum += __shfl_xor(sum, 32, 64);
        ssq += __shfl_xor(ssq, 16, 64); ssq += __shfl_xor(ssq, 32, 64);
        const float mean = sum * 0.015625f;
        const float var = ssq * 0.015625f - mean * mean;
        const float inv = rsqrtf(var + 1e-5f);
        const int e = ebase + t * 16 + er;
        if (e < E) {
#pragma unroll
            for (int m = 0; m < 4; ++m) {
                f32x4 o;
#pragma unroll
                for (int r = 0; r < 4; ++r) {
                    int f = 16 * m + 4 * a + r;
                    o[r] = (vals[4 * m + r] - mean) * inv * params[3][f] + params[4][f];
                }
                *(f32x4*)(out_edge + (size_t)e * 64 + 16 * m + 4 * a) = o;
            }
        }
    }
}

// ---------------- node MLP + LN (nodal16 bf16; linear reads) — R7 verbatim ----------------
__global__ __launch_bounds__(256) void node_mlp_kernel(
    const float* __restrict__ node_feat, const u16* __restrict__ nodal16,
    const u16* __restrict__ Pw,
    const float* __restrict__ b1g, const float* __restrict__ b2g, const float* __restrict__ b3g,
    const float* __restrict__ gg, const float* __restrict__ betag,
    float* __restrict__ out_node, int N)
{
    __shared__ float params[5][64];
    __shared__ u16 htile[4][1024];
    const int tid = threadIdx.x;
    if (tid < 64) {
        params[0][tid] = b1g[tid];
        params[1][tid] = b2g[tid];
        params[2][tid] = b3g[tid];
        params[3][tid] = gg[tid];
        params[4][tid] = betag[tid];
    }
    __syncthreads();
    const int wid = tid >> 6, lane = tid & 63;
    const int er = lane & 15, a = lane >> 4;
    const int nbase = (blockIdx.x * 4 + wid) * 16;
    if (nbase >= N) return;
    const int n = nbase + er;
    u16* ht = htile[wid];
    const int swz = (er & 7) << 4;

    f32x4 acc[4];
#pragma unroll
    for (int m = 0; m < 4; ++m) acc[m] = 0.0f;

#pragma unroll
    for (int s = 0; s < 4; ++s) {
        bf16x8 af[4];
#pragma unroll
        for (int m = 0; m < 4; ++m)
            af[m] = *(const bf16x8*)(Pw + PK_NW1 + ((s * 4 + m) * 64 + lane) * 8);
        bf16x8 bf;
        if (s < 2) bf = load8f_bf(node_feat + (size_t)n * 64 + s * 32 + a * 8);
        else       bf = *(const bf16x8*)(nodal16 + (size_t)n * 64 + (s - 2) * 32 + a * 8);
#pragma unroll
        for (int m = 0; m < 4; ++m)
            acc[m] = __builtin_amdgcn_mfma_f32_16x16x32_bf16(af[m], bf, acc[m], 0, 0, 0);
    }
#pragma unroll
    for (int m = 0; m < 4; ++m) {
        float v0 = fmaxf(acc[m][0] + params[0][16 * m + 4 * a + 0], 0.0f);
        float v1 = fmaxf(acc[m][1] + params[0][16 * m + 4 * a + 1], 0.0f);
        float v2 = fmaxf(acc[m][2] + params[0][16 * m + 4 * a + 2], 0.0f);
        float v3 = fmaxf(acc[m][3] + params[0][16 * m + 4 * a + 3], 0.0f);
        u32x2 pv; pv[0] = pk2(v0, v1); pv[1] = pk2(v2, v3);
        int boff = (er * 128 + (16 * m + 4 * a) * 2) ^ swz;
        *(u32x2*)((char*)ht + boff) = pv;
    }

#pragma unroll
    for (int m = 0; m < 4; ++m) acc[m] = 0.0f;
#pragma unroll
    for (int s = 0; s < 2; ++s) {
        bf16x8 af[4];
#pragma unroll
        for (int m = 0; m < 4; ++m)
            af[m] = *(const bf16x8*)(Pw + PK_NW2 + ((s * 4 + m) * 64 + lane) * 8);
        int boff = (er * 128 + s * 64 + a * 16) ^ swz;
        bf16x8 bf = *(const bf16x8*)((char*)ht + boff);
#pragma unroll
        for (int m = 0; m < 4; ++m)
            acc[m] = __builtin_amdgcn_mfma_f32_16x16x32_bf16(af[m], bf, acc[m], 0, 0, 0);
    }
#pragma unroll
    for (int m = 0; m < 4; ++m) {
        float v0 = fmaxf(acc[m][0] + params[1][16 * m + 4 * a + 0], 0.0f);
        float v1 = fmaxf(acc[m][1] + params[1][16 * m + 4 * a + 1], 0.0f);
        float v2 = fmaxf(acc[m][2] + params[1][16 * m + 4 * a + 2], 0.0f);
        float v3 = fmaxf(acc[m][3] + params[1][16 * m + 4 * a + 3], 0.0f);
        u32x2 pv; pv[0] = pk2(v0, v1); pv[1] = pk2(v2, v3);
        int boff = (er * 128 + (16 * m + 4 * a) * 2) ^ swz;
        *(u32x2*)((char*)ht + boff) = pv;
    }

#pragma unroll
    for (int m = 0; m < 4; ++m) acc[m] = 0.0f;
#pragma unroll
    for (int s = 0; s < 2; ++s) {
        bf16x8 af[4];
#pragma unroll
        for (int m = 0; m < 4; ++m)
            af[m] = *(const bf16x8*)(Pw + PK_NW3 + ((s * 4 + m) * 64 + lane) * 8);
        int boff = (er * 128 + s * 64 + a * 16) ^ swz;
        bf16x8 bf = *(const bf16x8*)((char*)ht + boff);
#pragma unroll
        for (int m = 0; m < 4; ++m)
            acc[m] = __builtin_amdgcn_mfma_f32_16x16x32_bf16(af[m], bf, acc[m], 0, 0, 0);
    }
    float vals[16], sum = 0.0f, ssq = 0.0f;
#pragma unroll
    for (int m = 0; m < 4; ++m)
#pragma unroll
        for (int r = 0; r < 4; ++r) {
            float v = acc[m][r] + params[2][16 * m + 4 * a + r];
            vals[4 * m + r] = v; sum += v; ssq += v * v;
        }
    sum += __shfl_xor(sum, 16, 64); sum += __shfl_xor(sum, 32, 64);
    ssq += __shfl_xor(ssq, 16, 64); ssq += __shfl_xor(ssq, 32, 64);
    const float mean = sum * 0.015625f;
    const float var = ssq * 0.015625f - mean * mean;
    const float inv = rsqrtf(var + 1e-5f);
#pragma unroll
    for (int m = 0; m < 4; ++m) {
        f32x4 o;
#pragma unroll
        for (int r = 0; r < 4; ++r) {
            int f = 16 * m + 4 * a + r;
            o[r] = (vals[4 * m + r] - mean) * inv * params[3][f] + params[4][f];
        }
        *(f32x4*)(out_node + (size_t)n * 64 + 16 * m + 4 * a) = o;
    }
}

extern "C" void kernel_launch(void* const* d_in, const int* in_sizes, int n_in,
                              void* d_out, int out_size, void* d_ws, size_t ws_size,
                              hipStream_t stream) {
    const float* node_feat = (const float*)d_in[0];
    const float* edge_feat = (const float*)d_in[1];
    const int* edge_idx  = (const int*)d_in[2];
    const float* eW1 = (const float*)d_in[4];
    const float* eb1 = (const float*)d_in[5];
    const float* eW2 = (const float*)d_in[6];
    const float* eb2 = (const float*)d_in[7];
    const float* eW3 = (const float*)d_in[8];
    const float* eb3 = (const float*)d_in[9];
    const float* eg  = (const float*)d_in[10];
    const float* ebt = (const float*)d_in[11];
    const float* nW1 = (const float*)d_in[12];
    const float* nb1 = (const float*)d_in[13];
    const float* nW2 = (const float*)d_in[14];
    const float* nb2 = (const float*)d_in[15];
    const float* nW3 = (const float*)d_in[16];
    const float* nb3 = (const float*)d_in[17];
    const float* ng  = (const float*)d_in[18];
    const float* nbt = (const float*)d_in[19];

    const int N = in_sizes[0] / 64;
    const int E = in_sizes[1] / 64;
    const int nparts = (N + 255) / 256;

    // ws layout
    char* w = (char*)d_ws;
    int* off      = (int*)w;                    w += (size_t)(N + 1) * 4;
    int* pos      = (int*)w;                    w += (size_t)N * 4;
    int* partials = (int*)w;                    w += 256 * 4;
    int* csr      = (int*)w;                    w += (size_t)E * 4;
    u16* Pw       = (u16*)w;                    w += (size_t)PK_TOTAL * 2;
    w = (char*)(((size_t)w + 255) & ~(size_t)255);
    u16* nodal16  = (u16*)w;                    // N*64 bf16

    float* out_edge = (float*)d_out;
    float* out_node = out_edge + (size_t)E * 64;

    pack_weights_kernel<<<(PK_TOTAL + 255) / 256, 256, 0, stream>>>(eW1, eW2, eW3, nW1, nW2, nW3, Pw);

    // edge MLP (512 threads, 512 edges per block, ET=4 weight-reuse)
    const int eblocks = (E + 511) / 512;
    edge_mlp_kernel<<<eblocks, 512, 0, stream>>>(node_feat, edge_feat, edge_idx, Pw,
                                                 eb1, eb2, eb3, eg, ebt, out_edge, E);

    // CSR build (pos doubles as degree histogram)
    hipMemsetAsync(pos, 0, (size_t)N * 4, stream);
    degree_kernel<<<(E + 255) / 256, 256, 0, stream>>>(edge_idx, pos, E);
    scan_blocks_kernel<<<nparts, 256, 0, stream>>>(pos, off, partials, N);
    scan_partials_kernel<<<1, 256, 0, stream>>>(partials, nparts);
    finalize_offsets_kernel<<<(N + 255) / 256, 256, 0, stream>>>(off, pos, partials, N, E);
    fill_csr_kernel<<<(E + 255) / 256, 256, 0, stream>>>(edge_idx, pos, csr, E);

    // segment-sum gather (fp32 rows -> bf16 nodal)
    gather_csr_kernel<<<(N + 3) / 4, 256, 0, stream>>>(out_edge, off, csr, nodal16, N);

    const int nblocks = (N + 63) / 64;
    node_mlp_kernel<<<nblocks, 256, 0, stream>>>(node_feat, nodal16, Pw,
                                                 nb1, nb2, nb3, ng, nbt, out_node, N);
}

// Round 15
// 578.900 us; speedup vs baseline: 1.1308x; 1.0318x over previous
//
#include <hip/hip_runtime.h>

typedef unsigned short u16;
typedef unsigned int u32;
typedef __attribute__((ext_vector_type(8))) __bf16 bf16x8;
typedef __attribute__((ext_vector_type(4))) float f32x4;
typedef __attribute__((ext_vector_type(2))) u32 u32x2;
typedef __attribute__((ext_vector_type(4))) u32 u32x4;

__device__ __forceinline__ u16 f2bf(float f) {
    u32 u = __float_as_uint(f);
    u = (u + 0x7FFFu + ((u >> 16) & 1u)) >> 16;
    return (u16)u;
}
__device__ __forceinline__ bf16x8 cvt2bf(f32x4 lo, f32x4 hi) {
    bf16x8 r;
    r[0] = (__bf16)lo[0]; r[1] = (__bf16)lo[1]; r[2] = (__bf16)lo[2]; r[3] = (__bf16)lo[3];
    r[4] = (__bf16)hi[0]; r[5] = (__bf16)hi[1]; r[6] = (__bf16)hi[2]; r[7] = (__bf16)hi[3];
    return r;
}
__device__ __forceinline__ bf16x8 load8f_bf(const float* p) {
    return cvt2bf(*(const f32x4*)p, *(const f32x4*)(p + 4));
}
__device__ __forceinline__ u32 pk2(float x, float y) {
    __bf16 bx = (__bf16)x, by = (__bf16)y;
    return (u32)__builtin_bit_cast(u16, bx) | ((u32)__builtin_bit_cast(u16, by) << 16);
}

// packed A-fragment (W^T) layout, per layer: idx = ((s*4 + m)*64 + lane)*8 + j
// value = W[k][16*m + (lane&15)], k = s*32 + (lane>>4)*8 + j
#define PK_EW1 0
#define PK_EW2 12288
#define PK_EW3 16384
#define PK_NW1 20480
#define PK_NW2 28672
#define PK_NW3 32768
#define PK_TOTAL 36864

__global__ void pack_weights_kernel(const float* __restrict__ eW1, const float* __restrict__ eW2,
                                    const float* __restrict__ eW3, const float* __restrict__ nW1,
                                    const float* __restrict__ nW2, const float* __restrict__ nW3,
                                    u16* __restrict__ P) {
    int idx = blockIdx.x * blockDim.x + threadIdx.x;
    if (idx >= PK_TOTAL) return;
    const float* W; int base;
    if (idx < PK_EW2)      { W = eW1; base = PK_EW1; }
    else if (idx < PK_EW3) { W = eW2; base = PK_EW2; }
    else if (idx < PK_NW1) { W = eW3; base = PK_EW3; }
    else if (idx < PK_NW2) { W = nW1; base = PK_NW1; }
    else if (idx < PK_NW3) { W = nW2; base = PK_NW2; }
    else                   { W = nW3; base = PK_NW3; }
    int r = idx - base;
    int j = r & 7, lane = (r >> 3) & 63, m = (r >> 9) & 3, s = r >> 11;
    int k = s * 32 + (lane >> 4) * 8 + j;
    int col = 16 * m + (lane & 15);
    P[idx] = f2bf(W[k * 64 + col]);
}

// ---------------- CSR build ----------------
__global__ void degree_kernel(const int* __restrict__ edge_idx, int* __restrict__ deg, int E) {
    int e = blockIdx.x * blockDim.x + threadIdx.x;
    if (e < E) atomicAdd(&deg[edge_idx[2 * e]], 1);
}

__global__ void scan_blocks_kernel(const int* __restrict__ deg, int* __restrict__ off,
                                   int* __restrict__ partials, int N) {
    __shared__ int sh[256];
    const int t = threadIdx.x;
    const int g = blockIdx.x * 256 + t;
    int v = (g < N) ? deg[g] : 0;
    sh[t] = v;
    __syncthreads();
#pragma unroll
    for (int d = 1; d < 256; d <<= 1) {
        int add = (t >= d) ? sh[t - d] : 0;
        __syncthreads();
        sh[t] += add;
        __syncthreads();
    }
    if (g < N) off[g] = sh[t] - v;
    if (t == 255) partials[blockIdx.x] = sh[255];
}

__global__ void scan_partials_kernel(int* __restrict__ partials, int nparts) {
    __shared__ int sh[256];
    const int t = threadIdx.x;
    int v = (t < nparts) ? partials[t] : 0;
    sh[t] = v;
    __syncthreads();
#pragma unroll
    for (int d = 1; d < 256; d <<= 1) {
        int add = (t >= d) ? sh[t - d] : 0;
        __syncthreads();
        sh[t] += add;
        __syncthreads();
    }
    if (t < nparts) partials[t] = sh[t] - v;
}

__global__ void finalize_offsets_kernel(int* __restrict__ off, int* __restrict__ pos,
                                        const int* __restrict__ partials, int N, int E) {
    int g = blockIdx.x * blockDim.x + threadIdx.x;
    if (g < N) {
        int o = off[g] + partials[g >> 8];
        off[g] = o;
        pos[g] = o;
    }
    if (g == 0) off[N] = E;
}

__global__ void fill_csr_kernel(const int* __restrict__ edge_idx, int* __restrict__ pos,
                                int* __restrict__ csr, int E) {
    int e = blockIdx.x * blockDim.x + threadIdx.x;
    if (e < E) {
        int slot = atomicAdd(&pos[edge_idx[2 * e]], 1);
        csr[slot] = e;
    }
}

// ---------------- segment-sum gather: one wave per node, 8 streams, bf16 output ----------------
__global__ __launch_bounds__(256) void gather_kernel(
    const float* __restrict__ proc_edge, const int* __restrict__ off,
    const int* __restrict__ csr, u16* __restrict__ nodal16, int N)
{
    const int wid = threadIdx.x >> 6, lane = threadIdx.x & 63;
    const int n = blockIdx.x * 4 + wid;
    if (n >= N) return;
    const int r = lane >> 4;      // row slot 0..3
    const int q = lane & 15;      // 4-float chunk within the 64-dim row
    const int beg = off[n], end = off[n + 1];
    f32x4 v0 = 0.0f, v1 = 0.0f, v2 = 0.0f, v3 = 0.0f;
    f32x4 v4 = 0.0f, v5 = 0.0f, v6 = 0.0f, v7 = 0.0f;
    int j = beg + r;
    for (; j + 28 < end; j += 32) {
        int e0 = csr[j],      e1 = csr[j + 4],  e2 = csr[j + 8],  e3 = csr[j + 12];
        int e4 = csr[j + 16], e5 = csr[j + 20], e6 = csr[j + 24], e7 = csr[j + 28];
        v0 += *(const f32x4*)(proc_edge + (size_t)e0 * 64 + q * 4);
        v1 += *(const f32x4*)(proc_edge + (size_t)e1 * 64 + q * 4);
        v2 += *(const f32x4*)(proc_edge + (size_t)e2 * 64 + q * 4);
        v3 += *(const f32x4*)(proc_edge + (size_t)e3 * 64 + q * 4);
        v4 += *(const f32x4*)(proc_edge + (size_t)e4 * 64 + q * 4);
        v5 += *(const f32x4*)(proc_edge + (size_t)e5 * 64 + q * 4);
        v6 += *(const f32x4*)(proc_edge + (size_t)e6 * 64 + q * 4);
        v7 += *(const f32x4*)(proc_edge + (size_t)e7 * 64 + q * 4);
    }
    for (; j + 12 < end; j += 16) {
        int e0 = csr[j], e1 = csr[j + 4], e2 = csr[j + 8], e3 = csr[j + 12];
        v0 += *(const f32x4*)(proc_edge + (size_t)e0 * 64 + q * 4);
        v1 += *(const f32x4*)(proc_edge + (size_t)e1 * 64 + q * 4);
        v2 += *(const f32x4*)(proc_edge + (size_t)e2 * 64 + q * 4);
        v3 += *(const f32x4*)(proc_edge + (size_t)e3 * 64 + q * 4);
    }
    for (; j < end; j += 4) {
        int e0 = csr[j];
        v0 += *(const f32x4*)(proc_edge + (size_t)e0 * 64 + q * 4);
    }
    v0 += v4; v1 += v5; v2 += v6; v3 += v7;
    v0 += v1; v2 += v3; v0 += v2;
#pragma unroll
    for (int i = 0; i < 4; ++i) {
        v0[i] += __shfl_xor(v0[i], 16, 64);
        v0[i] += __shfl_xor(v0[i], 32, 64);
    }
    if (r == 0) {
        u32x2 pv; pv[0] = pk2(v0[0], v0[1]); pv[1] = pk2(v0[2], v0[3]);
        *(u32x2*)(nodal16 + (size_t)n * 64 + q * 4) = pv;
    }
}

// ---------------- edge MLP + LN: 512 threads, two-phase weight staging (R7 verbatim) ----------------
#define ET 2
__global__ __launch_bounds__(512, 6) void edge_mlp_kernel(
    const float* __restrict__ node_feat, const float* __restrict__ edge_feat,
    const int* __restrict__ edge_idx, const u16* __restrict__ Pw,
    const float* __restrict__ b1g, const float* __restrict__ b2g, const float* __restrict__ b3g,
    const float* __restrict__ gg, const float* __restrict__ betag,
    float* __restrict__ out_edge, int E)
{
    __shared__ u16 wlds[12288];     // 24 KB: phase A = EW1; phase B = EW2|EW3
    __shared__ u16 htile[8][1024];  // per-wave 16x64 bf16 tile, XOR-swizzled
    __shared__ float params[5][64];
    const int tid = threadIdx.x;
    // ---- stage layer-1 weights (24 KB)
#pragma unroll
    for (int i = 0; i < 3; ++i) {
        int idx = i * 512 + tid;
        *(u32x4*)(wlds + (size_t)idx * 8) = *(const u32x4*)(Pw + PK_EW1 + (size_t)idx * 8);
    }
    if (tid < 64) {
        params[0][tid] = b1g[tid];
        params[1][tid] = b2g[tid];
        params[2][tid] = b3g[tid];
        params[3][tid] = gg[tid];
        params[4][tid] = betag[tid];
    }
    __syncthreads();

    const int wid = tid >> 6, lane = tid & 63;
    const int er = lane & 15, a = lane >> 4;
    const int ebase = (blockIdx.x * 8 + wid) * (16 * ET);
    u16* ht = htile[wid];
    const int swz = (er & 7) << 4;

    int eidx[ET], cn[ET], sn[ET];
#pragma unroll
    for (int t = 0; t < ET; ++t) {
        int e = ebase + t * 16 + er;
        if (e > E - 1) e = E - 1;
        eidx[t] = e;
        int2 ii = *(const int2*)(edge_idx + 2 * e);
        cn[t] = ii.x; sn[t] = ii.y;
    }

    f32x4 acc[ET][4];
#pragma unroll
    for (int t = 0; t < ET; ++t)
#pragma unroll
        for (int m = 0; m < 4; ++m) acc[t][m] = 0.0f;

    // ---- layer 1: K = 192; all 12 B-loads of a subtile issued before use
#pragma unroll
    for (int t = 0; t < ET; ++t) {
        f32x4 raw[12];
#pragma unroll
        for (int s = 0; s < 6; ++s) {
            const float* src;
            if (s < 2)      src = edge_feat + (size_t)eidx[t] * 64 + s * 32 + a * 8;
            else if (s < 4) src = node_feat + (size_t)cn[t] * 64 + (s - 2) * 32 + a * 8;
            else            src = node_feat + (size_t)sn[t] * 64 + (s - 4) * 32 + a * 8;
            raw[2 * s]     = *(const f32x4*)src;
            raw[2 * s + 1] = *(const f32x4*)(src + 4);
        }
#pragma unroll
        for (int s = 0; s < 6; ++s) {
            bf16x8 bf = cvt2bf(raw[2 * s], raw[2 * s + 1]);
#pragma unroll
            for (int m = 0; m < 4; ++m) {
                bf16x8 af = *(const bf16x8*)(wlds + ((s * 4 + m) * 64 + lane) * 8);
                acc[t][m] = __builtin_amdgcn_mfma_f32_16x16x32_bf16(af, bf, acc[t][m], 0, 0, 0);
            }
        }
    }
    __syncthreads();   // everyone done with layer-1 weights
    // ---- re-stage: EW2 | EW3 (16 KB) into the same buffer
#pragma unroll
    for (int i = 0; i < 2; ++i) {
        int idx = i * 512 + tid;
        *(u32x4*)(wlds + (size_t)idx * 8) = *(const u32x4*)(Pw + PK_EW2 + (size_t)idx * 8);
    }
    __syncthreads();

    // ---- layers 2 & 3 per subtile (weights from LDS: L2 at 0, L3 at 4096)
#pragma unroll
    for (int t = 0; t < ET; ++t) {
        // bias + relu (layer1) -> tile
#pragma unroll
        for (int m = 0; m < 4; ++m) {
            float v0 = fmaxf(acc[t][m][0] + params[0][16 * m + 4 * a + 0], 0.0f);
            float v1 = fmaxf(acc[t][m][1] + params[0][16 * m + 4 * a + 1], 0.0f);
            float v2 = fmaxf(acc[t][m][2] + params[0][16 * m + 4 * a + 2], 0.0f);
            float v3 = fmaxf(acc[t][m][3] + params[0][16 * m + 4 * a + 3], 0.0f);
            u32x2 pv; pv[0] = pk2(v0, v1); pv[1] = pk2(v2, v3);
            int boff = (er * 128 + (16 * m + 4 * a) * 2) ^ swz;
            *(u32x2*)((char*)ht + boff) = pv;
        }
        // layer 2: K = 64
        f32x4 a2[4];
#pragma unroll
        for (int m = 0; m < 4; ++m) a2[m] = 0.0f;
#pragma unroll
        for (int s = 0; s < 2; ++s) {
            int boff = (er * 128 + s * 64 + a * 16) ^ swz;
            bf16x8 bf = *(const bf16x8*)((char*)ht + boff);
#pragma unroll
            for (int m = 0; m < 4; ++m) {
                bf16x8 af = *(const bf16x8*)(wlds + ((s * 4 + m) * 64 + lane) * 8);
                a2[m] = __builtin_amdgcn_mfma_f32_16x16x32_bf16(af, bf, a2[m], 0, 0, 0);
            }
        }
        // bias + relu (layer2) -> tile (same-wave DS ops are in-order)
#pragma unroll
        for (int m = 0; m < 4; ++m) {
            float v0 = fmaxf(a2[m][0] + params[1][16 * m + 4 * a + 0], 0.0f);
            float v1 = fmaxf(a2[m][1] + params[1][16 * m + 4 * a + 1], 0.0f);
            float v2 = fmaxf(a2[m][2] + params[1][16 * m + 4 * a + 2], 0.0f);
            float v3 = fmaxf(a2[m][3] + params[1][16 * m + 4 * a + 3], 0.0f);
            u32x2 pv; pv[0] = pk2(v0, v1); pv[1] = pk2(v2, v3);
            int boff = (er * 128 + (16 * m + 4 * a) * 2) ^ swz;
            *(u32x2*)((char*)ht + boff) = pv;
        }
        // layer 3: K = 64 (no relu)
        f32x4 a3[4];
#pragma unroll
        for (int m = 0; m < 4; ++m) a3[m] = 0.0f;
#pragma unroll
        for (int s = 0; s < 2; ++s) {
            int boff = (er * 128 + s * 64 + a * 16) ^ swz;
            bf16x8 bf = *(const bf16x8*)((char*)ht + boff);
#pragma unroll
            for (int m = 0; m < 4; ++m) {
                bf16x8 af = *(const bf16x8*)(wlds + 4096 + ((s * 4 + m) * 64 + lane) * 8);
                a3[m] = __builtin_amdgcn_mfma_f32_16x16x32_bf16(af, bf, a3[m], 0, 0, 0);
            }
        }
        // LayerNorm + store
        float vals[16], sum = 0.0f, ssq = 0.0f;
#pragma unroll
        for (int m = 0; m < 4; ++m)
#pragma unroll
            for (int r = 0; r < 4; ++r) {
                float v = a3[m][r] + params[2][16 * m + 4 * a + r];
                vals[4 * m + r] = v; sum += v; ssq += v * v;
            }
        sum += __shfl_xor(sum, 16, 64); sum += __shfl_xor(sum, 32, 64);
        ssq += __shfl_xor(ssq, 16, 64); ssq += __shfl_xor(ssq, 32, 64);
        const float mean = sum * 0.015625f;
        const float var = ssq * 0.015625f - mean * mean;
        const float inv = rsqrtf(var + 1e-5f);
        const int e = ebase + t * 16 + er;
        if (e < E) {
#pragma unroll
            for (int m = 0; m < 4; ++m) {
                f32x4 o;
#pragma unroll
                for (int r = 0; r < 4; ++r) {
                    int f = 16 * m + 4 * a + r;
                    o[r] = (vals[4 * m + r] - mean) * inv * params[3][f] + params[4][f];
                }
                *(f32x4*)(out_edge + (size_t)e * 64 + 16 * m + 4 * a) = o;
            }
        }
    }
}

// ---------------- node MLP + LN (nodal precomputed as bf16; linear reads) — R7 verbatim ----------------
__global__ __launch_bounds__(256) void node_mlp_kernel(
    const float* __restrict__ node_feat, const u16* __restrict__ nodal16,
    const u16* __restrict__ Pw,
    const float* __restrict__ b1g, const float* __restrict__ b2g, const float* __restrict__ b3g,
    const float* __restrict__ gg, const float* __restrict__ betag,
    float* __restrict__ out_node, int N)
{
    __shared__ float params[5][64];
    __shared__ u16 htile[4][1024];
    const int tid = threadIdx.x;
    if (tid < 64) {
        params[0][tid] = b1g[tid];
        params[1][tid] = b2g[tid];
        params[2][tid] = b3g[tid];
        params[3][tid] = gg[tid];
        params[4][tid] = betag[tid];
    }
    __syncthreads();
    const int wid = tid >> 6, lane = tid & 63;
    const int er = lane & 15, a = lane >> 4;
    const int nbase = (blockIdx.x * 4 + wid) * 16;
    if (nbase >= N) return;
    const int n = nbase + er;
    u16* ht = htile[wid];
    const int swz = (er & 7) << 4;

    f32x4 acc[4];
#pragma unroll
    for (int m = 0; m < 4; ++m) acc[m] = 0.0f;

    // ---- layer 1: K = 128 (concat: node_feat | nodal_edge_feat[bf16])
#pragma unroll
    for (int s = 0; s < 4; ++s) {
        bf16x8 af[4];
#pragma unroll
        for (int m = 0; m < 4; ++m)
            af[m] = *(const bf16x8*)(Pw + PK_NW1 + ((s * 4 + m) * 64 + lane) * 8);
        bf16x8 bf;
        if (s < 2) bf = load8f_bf(node_feat + (size_t)n * 64 + s * 32 + a * 8);
        else       bf = *(const bf16x8*)(nodal16 + (size_t)n * 64 + (s - 2) * 32 + a * 8);
#pragma unroll
        for (int m = 0; m < 4; ++m)
            acc[m] = __builtin_amdgcn_mfma_f32_16x16x32_bf16(af[m], bf, acc[m], 0, 0, 0);
    }
#pragma unroll
    for (int m = 0; m < 4; ++m) {
        float v0 = fmaxf(acc[m][0] + params[0][16 * m + 4 * a + 0], 0.0f);
        float v1 = fmaxf(acc[m][1] + params[0][16 * m + 4 * a + 1], 0.0f);
        float v2 = fmaxf(acc[m][2] + params[0][16 * m + 4 * a + 2], 0.0f);
        float v3 = fmaxf(acc[m][3] + params[0][16 * m + 4 * a + 3], 0.0f);
        u32x2 pv; pv[0] = pk2(v0, v1); pv[1] = pk2(v2, v3);
        int boff = (er * 128 + (16 * m + 4 * a) * 2) ^ swz;
        *(u32x2*)((char*)ht + boff) = pv;
    }

    // ---- layer 2
#pragma unroll
    for (int m = 0; m < 4; ++m) acc[m] = 0.0f;
#pragma unroll
    for (int s = 0; s < 2; ++s) {
        bf16x8 af[4];
#pragma unroll
        for (int m = 0; m < 4; ++m)
            af[m] = *(const bf16x8*)(Pw + PK_NW2 + ((s * 4 + m) * 64 + lane) * 8);
        int boff = (er * 128 + s * 64 + a * 16) ^ swz;
        bf16x8 bf = *(const bf16x8*)((char*)ht + boff);
#pragma unroll
        for (int m = 0; m < 4; ++m)
            acc[m] = __builtin_amdgcn_mfma_f32_16x16x32_bf16(af[m], bf, acc[m], 0, 0, 0);
    }
#pragma unroll
    for (int m = 0; m < 4; ++m) {
        float v0 = fmaxf(acc[m][0] + params[1][16 * m + 4 * a + 0], 0.0f);
        float v1 = fmaxf(acc[m][1] + params[1][16 * m + 4 * a + 1], 0.0f);
        float v2 = fmaxf(acc[m][2] + params[1][16 * m + 4 * a + 2], 0.0f);
        float v3 = fmaxf(acc[m][3] + params[1][16 * m + 4 * a + 3], 0.0f);
        u32x2 pv; pv[0] = pk2(v0, v1); pv[1] = pk2(v2, v3);
        int boff = (er * 128 + (16 * m + 4 * a) * 2) ^ swz;
        *(u32x2*)((char*)ht + boff) = pv;
    }

    // ---- layer 3 + LN
#pragma unroll
    for (int m = 0; m < 4; ++m) acc[m] = 0.0f;
#pragma unroll
    for (int s = 0; s < 2; ++s) {
        bf16x8 af[4];
#pragma unroll
        for (int m = 0; m < 4; ++m)
            af[m] = *(const bf16x8*)(Pw + PK_NW3 + ((s * 4 + m) * 64 + lane) * 8);
        int boff = (er * 128 + s * 64 + a * 16) ^ swz;
        bf16x8 bf = *(const bf16x8*)((char*)ht + boff);
#pragma unroll
        for (int m = 0; m < 4; ++m)
            acc[m] = __builtin_amdgcn_mfma_f32_16x16x32_bf16(af[m], bf, acc[m], 0, 0, 0);
    }
    float vals[16], sum = 0.0f, ssq = 0.0f;
#pragma unroll
    for (int m = 0; m < 4; ++m)
#pragma unroll
        for (int r = 0; r < 4; ++r) {
            float v = acc[m][r] + params[2][16 * m + 4 * a + r];
            vals[4 * m + r] = v; sum += v; ssq += v * v;
        }
    sum += __shfl_xor(sum, 16, 64); sum += __shfl_xor(sum, 32, 64);
    ssq += __shfl_xor(ssq, 16, 64); ssq += __shfl_xor(ssq, 32, 64);
    const float mean = sum * 0.015625f;
    const float var = ssq * 0.015625f - mean * mean;
    const float inv = rsqrtf(var + 1e-5f);
#pragma unroll
    for (int m = 0; m < 4; ++m) {
        f32x4 o;
#pragma unroll
        for (int r = 0; r < 4; ++r) {
            int f = 16 * m + 4 * a + r;
            o[r] = (vals[4 * m + r] - mean) * inv * params[3][f] + params[4][f];
        }
        *(f32x4*)(out_node + (size_t)n * 64 + 16 * m + 4 * a) = o;
    }
}

extern "C" void kernel_launch(void* const* d_in, const int* in_sizes, int n_in,
                              void* d_out, int out_size, void* d_ws, size_t ws_size,
                              hipStream_t stream) {
    const float* node_feat = (const float*)d_in[0];
    const float* edge_feat = (const float*)d_in[1];
    const int* edge_idx  = (const int*)d_in[2];
    const float* eW1 = (const float*)d_in[4];
    const float* eb1 = (const float*)d_in[5];
    const float* eW2 = (const float*)d_in[6];
    const float* eb2 = (const float*)d_in[7];
    const float* eW3 = (const float*)d_in[8];
    const float* eb3 = (const float*)d_in[9];
    const float* eg  = (const float*)d_in[10];
    const float* ebt = (const float*)d_in[11];
    const float* nW1 = (const float*)d_in[12];
    const float* nb1 = (const float*)d_in[13];
    const float* nW2 = (const float*)d_in[14];
    const float* nb2 = (const float*)d_in[15];
    const float* nW3 = (const float*)d_in[16];
    const float* nb3 = (const float*)d_in[17];
    const float* ng  = (const float*)d_in[18];
    const float* nbt = (const float*)d_in[19];

    const int N = in_sizes[0] / 64;
    const int E = in_sizes[1] / 64;
    const int nparts = (N + 255) / 256;

    // ws layout
    char* w = (char*)d_ws;
    int* off      = (int*)w;                    w += (size_t)(N + 1) * 4;
    int* pos      = (int*)w;                    w += (size_t)N * 4;
    int* partials = (int*)w;                    w += 256 * 4;
    int* csr      = (int*)w;                    w += (size_t)E * 4;
    u16* Pw       = (u16*)w;                    w += (size_t)PK_TOTAL * 2;
    w = (char*)(((size_t)w + 255) & ~(size_t)255);
    u16* nodal16  = (u16*)w;                    // N*64 bf16

    float* out_edge = (float*)d_out;
    float* out_node = out_edge + (size_t)E * 64;

    pack_weights_kernel<<<(PK_TOTAL + 255) / 256, 256, 0, stream>>>(eW1, eW2, eW3, nW1, nW2, nW3, Pw);

    // edge MLP (512 threads, 256 edges per block) — R7's proven 285 µs kernel
    const int eblocks = (E + 255) / 256;
    edge_mlp_kernel<<<eblocks, 512, 0, stream>>>(node_feat, edge_feat, edge_idx, Pw,
                                                 eb1, eb2, eb3, eg, ebt, out_edge, E);

    // CSR build (pos doubles as degree histogram)
    hipMemsetAsync(pos, 0, (size_t)N * 4, stream);
    degree_kernel<<<(E + 255) / 256, 256, 0, stream>>>(edge_idx, pos, E);
    scan_blocks_kernel<<<nparts, 256, 0, stream>>>(pos, off, partials, N);
    scan_partials_kernel<<<1, 256, 0, stream>>>(partials, nparts);
    finalize_offsets_kernel<<<(N + 255) / 256, 256, 0, stream>>>(off, pos, partials, N, E);
    fill_csr_kernel<<<(E + 255) / 256, 256, 0, stream>>>(edge_idx, pos, csr, E);

    // wide segment-sum gather (one wave per node, 8 row streams)
    gather_kernel<<<(N + 3) / 4, 256, 0, stream>>>(out_edge, off, csr, nodal16, N);

    const int nblocks = (N + 63) / 64;
    node_mlp_kernel<<<nblocks, 256, 0, stream>>>(node_feat, nodal16, Pw,
                                                 nb1, nb2, nb3, ng, nbt, out_node, N);
}

// Round 16
// 578.532 us; speedup vs baseline: 1.1315x; 1.0006x over previous
//
#include <hip/hip_runtime.h>

typedef unsigned short u16;
typedef unsigned int u32;
typedef __attribute__((ext_vector_type(8))) __bf16 bf16x8;
typedef __attribute__((ext_vector_type(4))) float f32x4;
typedef __attribute__((ext_vector_type(2))) u32 u32x2;
typedef __attribute__((ext_vector_type(4))) u32 u32x4;

__device__ __forceinline__ u16 f2bf(float f) {
    u32 u = __float_as_uint(f);
    u = (u + 0x7FFFu + ((u >> 16) & 1u)) >> 16;
    return (u16)u;
}
__device__ __forceinline__ bf16x8 cvt2bf(f32x4 lo, f32x4 hi) {
    bf16x8 r;
    r[0] = (__bf16)lo[0]; r[1] = (__bf16)lo[1]; r[2] = (__bf16)lo[2]; r[3] = (__bf16)lo[3];
    r[4] = (__bf16)hi[0]; r[5] = (__bf16)hi[1]; r[6] = (__bf16)hi[2]; r[7] = (__bf16)hi[3];
    return r;
}
__device__ __forceinline__ bf16x8 load8f_bf(const float* p) {
    return cvt2bf(*(const f32x4*)p, *(const f32x4*)(p + 4));
}
__device__ __forceinline__ u32 pk2(float x, float y) {
    __bf16 bx = (__bf16)x, by = (__bf16)y;
    return (u32)__builtin_bit_cast(u16, bx) | ((u32)__builtin_bit_cast(u16, by) << 16);
}

// packed A-fragment (W^T) layout, per layer: idx = ((s*4 + m)*64 + lane)*8 + j
// value = W[k][16*m + (lane&15)], k = s*32 + (lane>>4)*8 + j
#define PK_EW1 0
#define PK_EW2 12288
#define PK_EW3 16384
#define PK_NW1 20480
#define PK_NW2 28672
#define PK_NW3 32768
#define PK_TOTAL 36864

__global__ void pack_weights_kernel(const float* __restrict__ eW1, const float* __restrict__ eW2,
                                    const float* __restrict__ eW3, const float* __restrict__ nW1,
                                    const float* __restrict__ nW2, const float* __restrict__ nW3,
                                    u16* __restrict__ P) {
    int idx = blockIdx.x * blockDim.x + threadIdx.x;
    if (idx >= PK_TOTAL) return;
    const float* W; int base;
    if (idx < PK_EW2)      { W = eW1; base = PK_EW1; }
    else if (idx < PK_EW3) { W = eW2; base = PK_EW2; }
    else if (idx < PK_NW1) { W = eW3; base = PK_EW3; }
    else if (idx < PK_NW2) { W = nW1; base = PK_NW1; }
    else if (idx < PK_NW3) { W = nW2; base = PK_NW2; }
    else                   { W = nW3; base = PK_NW3; }
    int r = idx - base;
    int j = r & 7, lane = (r >> 3) & 63, m = (r >> 9) & 3, s = r >> 11;
    int k = s * 32 + (lane >> 4) * 8 + j;
    int col = 16 * m + (lane & 15);
    P[idx] = f2bf(W[k * 64 + col]);
}

// ---------------- CSR build ----------------
__global__ void degree_kernel(const int* __restrict__ edge_idx, int* __restrict__ deg, int E) {
    int e = blockIdx.x * blockDim.x + threadIdx.x;
    if (e < E) atomicAdd(&deg[edge_idx[2 * e]], 1);
}

__global__ void scan_blocks_kernel(const int* __restrict__ deg, int* __restrict__ off,
                                   int* __restrict__ partials, int N) {
    __shared__ int sh[256];
    const int t = threadIdx.x;
    const int g = blockIdx.x * 256 + t;
    int v = (g < N) ? deg[g] : 0;
    sh[t] = v;
    __syncthreads();
#pragma unroll
    for (int d = 1; d < 256; d <<= 1) {
        int add = (t >= d) ? sh[t - d] : 0;
        __syncthreads();
        sh[t] += add;
        __syncthreads();
    }
    if (g < N) off[g] = sh[t] - v;
    if (t == 255) partials[blockIdx.x] = sh[255];
}

__global__ void scan_partials_kernel(int* __restrict__ partials, int nparts) {
    __shared__ int sh[256];
    const int t = threadIdx.x;
    int v = (t < nparts) ? partials[t] : 0;
    sh[t] = v;
    __syncthreads();
#pragma unroll
    for (int d = 1; d < 256; d <<= 1) {
        int add = (t >= d) ? sh[t - d] : 0;
        __syncthreads();
        sh[t] += add;
        __syncthreads();
    }
    if (t < nparts) partials[t] = sh[t] - v;
}

__global__ void finalize_offsets_kernel(int* __restrict__ off, int* __restrict__ pos,
                                        const int* __restrict__ partials, int N, int E) {
    int g = blockIdx.x * blockDim.x + threadIdx.x;
    if (g < N) {
        int o = off[g] + partials[g >> 8];
        off[g] = o;
        pos[g] = o;
    }
    if (g == 0) off[N] = E;
}

__global__ void fill_csr_kernel(const int* __restrict__ edge_idx, int* __restrict__ pos,
                                int* __restrict__ csr, int E) {
    int e = blockIdx.x * blockDim.x + threadIdx.x;
    if (e < E) {
        int slot = atomicAdd(&pos[edge_idx[2 * e]], 1);
        csr[slot] = e;
    }
}

// ---------------- segment-sum gather: one wave per node, 8 streams, bf16 output ----------------
__global__ __launch_bounds__(256) void gather_kernel(
    const float* __restrict__ proc_edge, const int* __restrict__ off,
    const int* __restrict__ csr, u16* __restrict__ nodal16, int N)
{
    const int wid = threadIdx.x >> 6, lane = threadIdx.x & 63;
    const int n = blockIdx.x * 4 + wid;
    if (n >= N) return;
    const int r = lane >> 4;      // row slot 0..3
    const int q = lane & 15;      // 4-float chunk within the 64-dim row
    const int beg = off[n], end = off[n + 1];
    f32x4 v0 = 0.0f, v1 = 0.0f, v2 = 0.0f, v3 = 0.0f;
    f32x4 v4 = 0.0f, v5 = 0.0f, v6 = 0.0f, v7 = 0.0f;
    int j = beg + r;
    for (; j + 28 < end; j += 32) {
        int e0 = csr[j],      e1 = csr[j + 4],  e2 = csr[j + 8],  e3 = csr[j + 12];
        int e4 = csr[j + 16], e5 = csr[j + 20], e6 = csr[j + 24], e7 = csr[j + 28];
        v0 += *(const f32x4*)(proc_edge + (size_t)e0 * 64 + q * 4);
        v1 += *(const f32x4*)(proc_edge + (size_t)e1 * 64 + q * 4);
        v2 += *(const f32x4*)(proc_edge + (size_t)e2 * 64 + q * 4);
        v3 += *(const f32x4*)(proc_edge + (size_t)e3 * 64 + q * 4);
        v4 += *(const f32x4*)(proc_edge + (size_t)e4 * 64 + q * 4);
        v5 += *(const f32x4*)(proc_edge + (size_t)e5 * 64 + q * 4);
        v6 += *(const f32x4*)(proc_edge + (size_t)e6 * 64 + q * 4);
        v7 += *(const f32x4*)(proc_edge + (size_t)e7 * 64 + q * 4);
    }
    for (; j + 12 < end; j += 16) {
        int e0 = csr[j], e1 = csr[j + 4], e2 = csr[j + 8], e3 = csr[j + 12];
        v0 += *(const f32x4*)(proc_edge + (size_t)e0 * 64 + q * 4);
        v1 += *(const f32x4*)(proc_edge + (size_t)e1 * 64 + q * 4);
        v2 += *(const f32x4*)(proc_edge + (size_t)e2 * 64 + q * 4);
        v3 += *(const f32x4*)(proc_edge + (size_t)e3 * 64 + q * 4);
    }
    for (; j < end; j += 4) {
        int e0 = csr[j];
        v0 += *(const f32x4*)(proc_edge + (size_t)e0 * 64 + q * 4);
    }
    v0 += v4; v1 += v5; v2 += v6; v3 += v7;
    v0 += v1; v2 += v3; v0 += v2;
#pragma unroll
    for (int i = 0; i < 4; ++i) {
        v0[i] += __shfl_xor(v0[i], 16, 64);
        v0[i] += __shfl_xor(v0[i], 32, 64);
    }
    if (r == 0) {
        u32x2 pv; pv[0] = pk2(v0[0], v0[1]); pv[1] = pk2(v0[2], v0[3]);
        *(u32x2*)(nodal16 + (size_t)n * 64 + q * 4) = pv;
    }
}

// ---------------- edge MLP + LN: R15 structure + inline-asm batched layer-1 loads ----------------
#define ET 2
__global__ __launch_bounds__(512, 4) void edge_mlp_kernel(
    const float* __restrict__ node_feat, const float* __restrict__ edge_feat,
    const int* __restrict__ edge_idx, const u16* __restrict__ Pw,
    const float* __restrict__ b1g, const float* __restrict__ b2g, const float* __restrict__ b3g,
    const float* __restrict__ gg, const float* __restrict__ betag,
    float* __restrict__ out_edge, int E)
{
    __shared__ u16 wlds[12288];     // 24 KB: phase A = EW1; phase B = EW2|EW3
    __shared__ u16 htile[8][1024];  // per-wave 16x64 bf16 tile, XOR-swizzled
    __shared__ float params[5][64];
    const int tid = threadIdx.x;
    // ---- stage layer-1 weights (24 KB)
#pragma unroll
    for (int i = 0; i < 3; ++i) {
        int idx = i * 512 + tid;
        *(u32x4*)(wlds + (size_t)idx * 8) = *(const u32x4*)(Pw + PK_EW1 + (size_t)idx * 8);
    }
    if (tid < 64) {
        params[0][tid] = b1g[tid];
        params[1][tid] = b2g[tid];
        params[2][tid] = b3g[tid];
        params[3][tid] = gg[tid];
        params[4][tid] = betag[tid];
    }
    __syncthreads();

    const int wid = tid >> 6, lane = tid & 63;
    const int er = lane & 15, a = lane >> 4;
    const int ebase = (blockIdx.x * 8 + wid) * (16 * ET);
    u16* ht = htile[wid];
    const int swz = (er & 7) << 4;

    int eidx[ET], cn[ET], sn[ET];
#pragma unroll
    for (int t = 0; t < ET; ++t) {
        int e = ebase + t * 16 + er;
        if (e > E - 1) e = E - 1;
        eidx[t] = e;
        int2 ii = *(const int2*)(edge_idx + 2 * e);
        cn[t] = ii.x; sn[t] = ii.y;
    }

    f32x4 acc[ET][4];
#pragma unroll
    for (int t = 0; t < ET; ++t)
#pragma unroll
        for (int m = 0; m < 4; ++m) acc[t][m] = 0.0f;

    // ---- layer 1: K = 192; 12 loads per subtile FORCED in flight via volatile asm
#pragma unroll
    for (int t = 0; t < ET; ++t) {
        const float* pe = edge_feat + (size_t)eidx[t] * 64 + a * 8;
        const float* pc = node_feat + (size_t)cn[t] * 64 + a * 8;
        const float* ps = node_feat + (size_t)sn[t] * 64 + a * 8;
        f32x4 r0, r1, r2, r3, r4, r5, r6, r7, r8, r9, r10, r11;
        asm volatile("global_load_dwordx4 %0, %1, off" : "=v"(r0)  : "v"(pe));
        asm volatile("global_load_dwordx4 %0, %1, off" : "=v"(r1)  : "v"(pe + 4));
        asm volatile("global_load_dwordx4 %0, %1, off" : "=v"(r2)  : "v"(pe + 32));
        asm volatile("global_load_dwordx4 %0, %1, off" : "=v"(r3)  : "v"(pe + 36));
        asm volatile("global_load_dwordx4 %0, %1, off" : "=v"(r4)  : "v"(pc));
        asm volatile("global_load_dwordx4 %0, %1, off" : "=v"(r5)  : "v"(pc + 4));
        asm volatile("global_load_dwordx4 %0, %1, off" : "=v"(r6)  : "v"(pc + 32));
        asm volatile("global_load_dwordx4 %0, %1, off" : "=v"(r7)  : "v"(pc + 36));
        asm volatile("global_load_dwordx4 %0, %1, off" : "=v"(r8)  : "v"(ps));
        asm volatile("global_load_dwordx4 %0, %1, off" : "=v"(r9)  : "v"(ps + 4));
        asm volatile("global_load_dwordx4 %0, %1, off" : "=v"(r10) : "v"(ps + 32));
        asm volatile("global_load_dwordx4 %0, %1, off" : "=v"(r11) : "v"(ps + 36));
        asm volatile("s_waitcnt vmcnt(0)"
                     : "+v"(r0), "+v"(r1), "+v"(r2), "+v"(r3), "+v"(r4), "+v"(r5),
                       "+v"(r6), "+v"(r7), "+v"(r8), "+v"(r9), "+v"(r10), "+v"(r11)
                     :
                     : "memory");
        __builtin_amdgcn_sched_barrier(0);
        f32x4 raw[12] = {r0, r1, r2, r3, r4, r5, r6, r7, r8, r9, r10, r11};
#pragma unroll
        for (int s = 0; s < 6; ++s) {
            bf16x8 bf = cvt2bf(raw[2 * s], raw[2 * s + 1]);
#pragma unroll
            for (int m = 0; m < 4; ++m) {
                bf16x8 af = *(const bf16x8*)(wlds + ((s * 4 + m) * 64 + lane) * 8);
                acc[t][m] = __builtin_amdgcn_mfma_f32_16x16x32_bf16(af, bf, acc[t][m], 0, 0, 0);
            }
        }
    }
    __syncthreads();   // everyone done with layer-1 weights
    // ---- re-stage: EW2 | EW3 (16 KB) into the same buffer
#pragma unroll
    for (int i = 0; i < 2; ++i) {
        int idx = i * 512 + tid;
        *(u32x4*)(wlds + (size_t)idx * 8) = *(const u32x4*)(Pw + PK_EW2 + (size_t)idx * 8);
    }
    __syncthreads();

    // ---- layers 2 & 3 per subtile (weights from LDS: L2 at 0, L3 at 4096)
#pragma unroll
    for (int t = 0; t < ET; ++t) {
        // bias + relu (layer1) -> tile
#pragma unroll
        for (int m = 0; m < 4; ++m) {
            float v0 = fmaxf(acc[t][m][0] + params[0][16 * m + 4 * a + 0], 0.0f);
            float v1 = fmaxf(acc[t][m][1] + params[0][16 * m + 4 * a + 1], 0.0f);
            float v2 = fmaxf(acc[t][m][2] + params[0][16 * m + 4 * a + 2], 0.0f);
            float v3 = fmaxf(acc[t][m][3] + params[0][16 * m + 4 * a + 3], 0.0f);
            u32x2 pv; pv[0] = pk2(v0, v1); pv[1] = pk2(v2, v3);
            int boff = (er * 128 + (16 * m + 4 * a) * 2) ^ swz;
            *(u32x2*)((char*)ht + boff) = pv;
        }
        // layer 2: K = 64
        f32x4 a2[4];
#pragma unroll
        for (int m = 0; m < 4; ++m) a2[m] = 0.0f;
#pragma unroll
        for (int s = 0; s < 2; ++s) {
            int boff = (er * 128 + s * 64 + a * 16) ^ swz;
            bf16x8 bf = *(const bf16x8*)((char*)ht + boff);
#pragma unroll
            for (int m = 0; m < 4; ++m) {
                bf16x8 af = *(const bf16x8*)(wlds + ((s * 4 + m) * 64 + lane) * 8);
                a2[m] = __builtin_amdgcn_mfma_f32_16x16x32_bf16(af, bf, a2[m], 0, 0, 0);
            }
        }
        // bias + relu (layer2) -> tile (same-wave DS ops are in-order)
#pragma unroll
        for (int m = 0; m < 4; ++m) {
            float v0 = fmaxf(a2[m][0] + params[1][16 * m + 4 * a + 0], 0.0f);
            float v1 = fmaxf(a2[m][1] + params[1][16 * m + 4 * a + 1], 0.0f);
            float v2 = fmaxf(a2[m][2] + params[1][16 * m + 4 * a + 2], 0.0f);
            float v3 = fmaxf(a2[m][3] + params[1][16 * m + 4 * a + 3], 0.0f);
            u32x2 pv; pv[0] = pk2(v0, v1); pv[1] = pk2(v2, v3);
            int boff = (er * 128 + (16 * m + 4 * a) * 2) ^ swz;
            *(u32x2*)((char*)ht + boff) = pv;
        }
        // layer 3: K = 64 (no relu)
        f32x4 a3[4];
#pragma unroll
        for (int m = 0; m < 4; ++m) a3[m] = 0.0f;
#pragma unroll
        for (int s = 0; s < 2; ++s) {
            int boff = (er * 128 + s * 64 + a * 16) ^ swz;
            bf16x8 bf = *(const bf16x8*)((char*)ht + boff);
#pragma unroll
            for (int m = 0; m < 4; ++m) {
                bf16x8 af = *(const bf16x8*)(wlds + 4096 + ((s * 4 + m) * 64 + lane) * 8);
                a3[m] = __builtin_amdgcn_mfma_f32_16x16x32_bf16(af, bf, a3[m], 0, 0, 0);
            }
        }
        // LayerNorm + store
        float vals[16], sum = 0.0f, ssq = 0.0f;
#pragma unroll
        for (int m = 0; m < 4; ++m)
#pragma unroll
            for (int r = 0; r < 4; ++r) {
                float v = a3[m][r] + params[2][16 * m + 4 * a + r];
                vals[4 * m + r] = v; sum += v; ssq += v * v;
            }
        sum += __shfl_xor(sum, 16, 64); sum += __shfl_xor(sum, 32, 64);
        ssq += __shfl_xor(ssq, 16, 64); ssq += __shfl_xor(ssq, 32, 64);
        const float mean = sum * 0.015625f;
        const float var = ssq * 0.015625f - mean * mean;
        const float inv = rsqrtf(var + 1e-5f);
        const int e = ebase + t * 16 + er;
        if (e < E) {
#pragma unroll
            for (int m = 0; m < 4; ++m) {
                f32x4 o;
#pragma unroll
                for (int r = 0; r < 4; ++r) {
                    int f = 16 * m + 4 * a + r;
                    o[r] = (vals[4 * m + r] - mean) * inv * params[3][f] + params[4][f];
                }
                *(f32x4*)(out_edge + (size_t)e * 64 + 16 * m + 4 * a) = o;
            }
        }
    }
}

// ---------------- node MLP + LN (nodal precomputed as bf16; linear reads) — R7 verbatim ----------------
__global__ __launch_bounds__(256) void node_mlp_kernel(
    const float* __restrict__ node_feat, const u16* __restrict__ nodal16,
    const u16* __restrict__ Pw,
    const float* __restrict__ b1g, const float* __restrict__ b2g, const float* __restrict__ b3g,
    const float* __restrict__ gg, const float* __restrict__ betag,
    float* __restrict__ out_node, int N)
{
    __shared__ float params[5][64];
    __shared__ u16 htile[4][1024];
    const int tid = threadIdx.x;
    if (tid < 64) {
        params[0][tid] = b1g[tid];
        params[1][tid] = b2g[tid];
        params[2][tid] = b3g[tid];
        params[3][tid] = gg[tid];
        params[4][tid] = betag[tid];
    }
    __syncthreads();
    const int wid = tid >> 6, lane = tid & 63;
    const int er = lane & 15, a = lane >> 4;
    const int nbase = (blockIdx.x * 4 + wid) * 16;
    if (nbase >= N) return;
    const int n = nbase + er;
    u16* ht = htile[wid];
    const int swz = (er & 7) << 4;

    f32x4 acc[4];
#pragma unroll
    for (int m = 0; m < 4; ++m) acc[m] = 0.0f;

    // ---- layer 1: K = 128 (concat: node_feat | nodal_edge_feat[bf16])
#pragma unroll
    for (int s = 0; s < 4; ++s) {
        bf16x8 af[4];
#pragma unroll
        for (int m = 0; m < 4; ++m)
            af[m] = *(const bf16x8*)(Pw + PK_NW1 + ((s * 4 + m) * 64 + lane) * 8);
        bf16x8 bf;
        if (s < 2) bf = load8f_bf(node_feat + (size_t)n * 64 + s * 32 + a * 8);
        else       bf = *(const bf16x8*)(nodal16 + (size_t)n * 64 + (s - 2) * 32 + a * 8);
#pragma unroll
        for (int m = 0; m < 4; ++m)
            acc[m] = __builtin_amdgcn_mfma_f32_16x16x32_bf16(af[m], bf, acc[m], 0, 0, 0);
    }
#pragma unroll
    for (int m = 0; m < 4; ++m) {
        float v0 = fmaxf(acc[m][0] + params[0][16 * m + 4 * a + 0], 0.0f);
        float v1 = fmaxf(acc[m][1] + params[0][16 * m + 4 * a + 1], 0.0f);
        float v2 = fmaxf(acc[m][2] + params[0][16 * m + 4 * a + 2], 0.0f);
        float v3 = fmaxf(acc[m][3] + params[0][16 * m + 4 * a + 3], 0.0f);
        u32x2 pv; pv[0] = pk2(v0, v1); pv[1] = pk2(v2, v3);
        int boff = (er * 128 + (16 * m + 4 * a) * 2) ^ swz;
        *(u32x2*)((char*)ht + boff) = pv;
    }

    // ---- layer 2
#pragma unroll
    for (int m = 0; m < 4; ++m) acc[m] = 0.0f;
#pragma unroll
    for (int s = 0; s < 2; ++s) {
        bf16x8 af[4];
#pragma unroll
        for (int m = 0; m < 4; ++m)
            af[m] = *(const bf16x8*)(Pw + PK_NW2 + ((s * 4 + m) * 64 + lane) * 8);
        int boff = (er * 128 + s * 64 + a * 16) ^ swz;
        bf16x8 bf = *(const bf16x8*)((char*)ht + boff);
#pragma unroll
        for (int m = 0; m < 4; ++m)
            acc[m] = __builtin_amdgcn_mfma_f32_16x16x32_bf16(af[m], bf, acc[m], 0, 0, 0);
    }
#pragma unroll
    for (int m = 0; m < 4; ++m) {
        float v0 = fmaxf(acc[m][0] + params[1][16 * m + 4 * a + 0], 0.0f);
        float v1 = fmaxf(acc[m][1] + params[1][16 * m + 4 * a + 1], 0.0f);
        float v2 = fmaxf(acc[m][2] + params[1][16 * m + 4 * a + 2], 0.0f);
        float v3 = fmaxf(acc[m][3] + params[1][16 * m + 4 * a + 3], 0.0f);
        u32x2 pv; pv[0] = pk2(v0, v1); pv[1] = pk2(v2, v3);
        int boff = (er * 128 + (16 * m + 4 * a) * 2) ^ swz;
        *(u32x2*)((char*)ht + boff) = pv;
    }

    // ---- layer 3 + LN
#pragma unroll
    for (int m = 0; m < 4; ++m) acc[m] = 0.0f;
#pragma unroll
    for (int s = 0; s < 2; ++s) {
        bf16x8 af[4];
#pragma unroll
        for (int m = 0; m < 4; ++m)
            af[m] = *(const bf16x8*)(Pw + PK_NW3 + ((s * 4 + m) * 64 + lane) * 8);
        int boff = (er * 128 + s * 64 + a * 16) ^ swz;
        bf16x8 bf = *(const bf16x8*)((char*)ht + boff);
#pragma unroll
        for (int m = 0; m < 4; ++m)
            acc[m] = __builtin_amdgcn_mfma_f32_16x16x32_bf16(af[m], bf, acc[m], 0, 0, 0);
    }
    float vals[16], sum = 0.0f, ssq = 0.0f;
#pragma unroll
    for (int m = 0; m < 4; ++m)
#pragma unroll
        for (int r = 0; r < 4; ++r) {
            float v = acc[m][r] + params[2][16 * m + 4 * a + r];
            vals[4 * m + r] = v; sum += v; ssq += v * v;
        }
    sum += __shfl_xor(sum, 16, 64); sum += __shfl_xor(sum, 32, 64);
    ssq += __shfl_xor(ssq, 16, 64); ssq += __shfl_xor(ssq, 32, 64);
    const float mean = sum * 0.015625f;
    const float var = ssq * 0.015625f - mean * mean;
    const float inv = rsqrtf(var + 1e-5f);
#pragma unroll
    for (int m = 0; m < 4; ++m) {
        f32x4 o;
#pragma unroll
        for (int r = 0; r < 4; ++r) {
            int f = 16 * m + 4 * a + r;
            o[r] = (vals[4 * m + r] - mean) * inv * params[3][f] + params[4][f];
        }
        *(f32x4*)(out_node + (size_t)n * 64 + 16 * m + 4 * a) = o;
    }
}

extern "C" void kernel_launch(void* const* d_in, const int* in_sizes, int n_in,
                              void* d_out, int out_size, void* d_ws, size_t ws_size,
                              hipStream_t stream) {
    const float* node_feat = (const float*)d_in[0];
    const float* edge_feat = (const float*)d_in[1];
    const int* edge_idx  = (const int*)d_in[2];
    const float* eW1 = (const float*)d_in[4];
    const float* eb1 = (const float*)d_in[5];
    const float* eW2 = (const float*)d_in[6];
    const float* eb2 = (const float*)d_in[7];
    const float* eW3 = (const float*)d_in[8];
    const float* eb3 = (const float*)d_in[9];
    const float* eg  = (const float*)d_in[10];
    const float* ebt = (const float*)d_in[11];
    const float* nW1 = (const float*)d_in[12];
    const float* nb1 = (const float*)d_in[13];
    const float* nW2 = (const float*)d_in[14];
    const float* nb2 = (const float*)d_in[15];
    const float* nW3 = (const float*)d_in[16];
    const float* nb3 = (const float*)d_in[17];
    const float* ng  = (const float*)d_in[18];
    const float* nbt = (const float*)d_in[19];

    const int N = in_sizes[0] / 64;
    const int E = in_sizes[1] / 64;
    const int nparts = (N + 255) / 256;

    // ws layout
    char* w = (char*)d_ws;
    int* off      = (int*)w;                    w += (size_t)(N + 1) * 4;
    int* pos      = (int*)w;                    w += (size_t)N * 4;
    int* partials = (int*)w;                    w += 256 * 4;
    int* csr      = (int*)w;                    w += (size_t)E * 4;
    u16* Pw       = (u16*)w;                    w += (size_t)PK_TOTAL * 2;
    w = (char*)(((size_t)w + 255) & ~(size_t)255);
    u16* nodal16  = (u16*)w;                    // N*64 bf16

    float* out_edge = (float*)d_out;
    float* out_node = out_edge + (size_t)E * 64;

    pack_weights_kernel<<<(PK_TOTAL + 255) / 256, 256, 0, stream>>>(eW1, eW2, eW3, nW1, nW2, nW3, Pw);

    // edge MLP (512 threads, 256 edges per block; asm-batched layer-1 loads)
    const int eblocks = (E + 255) / 256;
    edge_mlp_kernel<<<eblocks, 512, 0, stream>>>(node_feat, edge_feat, edge_idx, Pw,
                                                 eb1, eb2, eb3, eg, ebt, out_edge, E);

    // CSR build (pos doubles as degree histogram)
    hipMemsetAsync(pos, 0, (size_t)N * 4, stream);
    degree_kernel<<<(E + 255) / 256, 256, 0, stream>>>(edge_idx, pos, E);
    scan_blocks_kernel<<<nparts, 256, 0, stream>>>(pos, off, partials, N);
    scan_partials_kernel<<<1, 256, 0, stream>>>(partials, nparts);
    finalize_offsets_kernel<<<(N + 255) / 256, 256, 0, stream>>>(off, pos, partials, N, E);
    fill_csr_kernel<<<(E + 255) / 256, 256, 0, stream>>>(edge_idx, pos, csr, E);

    // wide segment-sum gather (one wave per node, 8 row streams)
    gather_kernel<<<(N + 3) / 4, 256, 0, stream>>>(out_edge, off, csr, nodal16, N);

    const int nblocks = (N + 63) / 64;
    node_mlp_kernel<<<nblocks, 256, 0, stream>>>(node_feat, nodal16, Pw,
                                                 nb1, nb2, nb3, ng, nbt, out_node, N);
}